// Round 1
// baseline (3661.613 us; speedup 1.0000x reference)
//
#include <hip/hip_runtime.h>
#include <hip/hip_bf16.h>

#define DEV __device__ __forceinline__

constexpr int BATCH_ = 4;
constexpr int N1_ = 131072;
constexpr int N2_ = 32768;
constexpr int L1_ = N1_ / BATCH_;   // 32768
constexpr int L2_ = N2_ / BATCH_;   // 8192
constexpr int DM_ = 128;
constexpr int DI_ = 256;
constexpr int DS_ = 16;
constexpr int DTR_ = 8;
constexpr int TOT_ = N1_ + N2_;     // 163840

constexpr int TA_ = 32;             // phase A / final tile (tokens)
constexpr int TAH_ = TA_ + 3;       // + conv halo
constexpr int NTILE1_ = L1_ / TA_;  // 1024
constexpr int NTILE2_ = L2_ / TA_;  // 256
constexpr int NTILES_ = 4 * NTILE1_ + 4 * NTILE2_;  // 5120

constexpr int TS_ = 128;            // scan chunk length
constexpr int NCH1_ = L1_ / TS_;    // 256
constexpr int NCH2_ = L2_ / TS_;    // 64
constexpr int NCHUNKS_ = 4 * NCH1_ + 4 * NCH2_;     // 1280

struct MP {
  const float* ln_g; const float* ln_b; const float* in_w;
  const float* conv_w; const float* conv_b; const float* xproj_w;
  const float* dtproj_w; const float* dtproj_b; const float* A_log;
  const float* Dp; const float* out_w;
};

DEV float softplusf(float x) {
  return fmaxf(x, 0.f) + log1pf(__expf(-fabsf(x)));
}

DEV float dot16f(const float* hp, const float4& w0, const float4& w1,
                 const float4& w2, const float4& w3) {
  const float4 h0 = *(const float4*)(hp);
  const float4 h1 = *(const float4*)(hp + 4);
  const float4 h2 = *(const float4*)(hp + 8);
  const float4 h3 = *(const float4*)(hp + 12);
  return h0.x*w0.x + h0.y*w0.y + h0.z*w0.z + h0.w*w0.w
       + h1.x*w1.x + h1.y*w1.y + h1.z*w1.z + h1.w*w1.w
       + h2.x*w2.x + h2.y*w2.y + h2.z*w2.z + h2.w*w2.w
       + h3.x*w3.x + h3.y*w3.y + h3.z*w3.z + h3.w*w3.w;
}

// ---------------------------------------------------------------------------
// Stable per-segment argsort: LSD radix, 4-bit digits, 8 passes. 1 block/segment.
// ---------------------------------------------------------------------------
__global__ __launch_bounds__(512) void k_sort(
    const int* __restrict__ hil1, const int* __restrict__ hil2,
    int* __restrict__ o_all,
    unsigned* __restrict__ kA, int* __restrict__ iA,
    unsigned* __restrict__ kB, int* __restrict__ iB)
{
  const int seg = blockIdx.x;
  int n, slotbase; const int* src;
  if (seg < 4) { n = L1_; src = hil1 + seg * L1_; slotbase = seg * L1_; }
  else { n = L2_; src = hil2 + (seg - 4) * L2_; slotbase = N1_ + (seg - 4) * L2_; }
  unsigned* keyA = kA + slotbase; int* idxA = iA + slotbase;
  unsigned* keyB = kB + slotbase; int* idxB = iB + slotbase;
  const int tid = threadIdx.x;
  const int C = n >> 9;   // n / 512 elements per thread, contiguous (stability)
  __shared__ unsigned cnt[16 * 512];
  __shared__ unsigned wsum[8];
  for (int pass = 0; pass < 8; ++pass) {
    const int shift = pass * 4;
    #pragma unroll
    for (int d = 0; d < 16; ++d) cnt[d * 512 + tid] = 0;
    __syncthreads();
    const unsigned* ksrc = (pass & 1) ? keyB : keyA;
    const int* isrc = (pass & 1) ? idxB : idxA;
    if (pass == 0) {
      for (int j = 0; j < C; ++j) {
        unsigned k = (unsigned)src[tid * C + j];
        cnt[((k >> shift) & 15u) * 512 + tid]++;
      }
    } else {
      for (int j = 0; j < C; ++j) {
        unsigned k = ksrc[tid * C + j];
        cnt[((k >> shift) & 15u) * 512 + tid]++;
      }
    }
    __syncthreads();
    // exclusive scan over flat 8192 counts (digit-major, thread-minor order)
    unsigned loc[16]; unsigned tot = 0;
    #pragma unroll
    for (int j = 0; j < 16; ++j) { loc[j] = tot; tot += cnt[tid * 16 + j]; }
    const int lane = tid & 63, wv = tid >> 6;
    unsigned inc = tot;
    #pragma unroll
    for (int off = 1; off < 64; off <<= 1) {
      unsigned v = (unsigned)__shfl_up((int)inc, off, 64);
      if (lane >= off) inc += v;
    }
    if (lane == 63) wsum[wv] = inc;
    __syncthreads();
    unsigned wbase = 0;
    for (int w2 = 0; w2 < 8; ++w2) if (w2 < wv) wbase += wsum[w2];
    const unsigned excl = wbase + inc - tot;
    #pragma unroll
    for (int j = 0; j < 16; ++j) cnt[tid * 16 + j] = excl + loc[j];
    __syncthreads();
    unsigned mybase[16];
    #pragma unroll
    for (int d = 0; d < 16; ++d) mybase[d] = cnt[d * 512 + tid];
    unsigned* kdst = (pass & 1) ? keyA : keyB;
    int* idst = (pass & 1) ? idxA : idxB;
    if (pass == 0) {
      for (int j = 0; j < C; ++j) {
        const int i = tid * C + j;
        const unsigned k = (unsigned)src[i];
        const unsigned d = (k >> shift) & 15u;
        const unsigned pos = mybase[d]++;
        kdst[pos] = k; idst[pos] = i;
      }
    } else {
      for (int j = 0; j < C; ++j) {
        const int i = tid * C + j;
        const unsigned k = ksrc[i];
        const unsigned d = (k >> shift) & 15u;
        const unsigned pos = mybase[d]++;
        kdst[pos] = k; idst[pos] = isrc[i];
      }
    }
    __syncthreads();
  }
  for (int j = 0; j < C; ++j) {
    const int i = tid * C + j;
    o_all[slotbase + i] = idxA[i];   // 8 passes end in buffer A
  }
}

// ---------------------------------------------------------------------------
// Phase A: gather+embed -> LN -> in_proj(xc,z) -> conv+silu -> x_proj
// One block per 32-token tile (+3 halo). Outputs: xc(bf16), z(bf16), dbl(fp32,40)
// ---------------------------------------------------------------------------
__global__ __launch_bounds__(256) void k_phaseA(
    const float* __restrict__ feats1, const float* __restrict__ feats2,
    const float* __restrict__ pos1, const float* __restrict__ pos2,
    const float* __restrict__ pe_w, const float* __restrict__ pe_b,
    MP p1, MP p2, const int* __restrict__ o_all,
    __hip_bfloat16* __restrict__ xc_g, __hip_bfloat16* __restrict__ z_g,
    float* __restrict__ dbl_g)
{
  const int blk = blockIdx.x;
  bool is1; int b, tile;
  if (blk < 4 * NTILE1_) { is1 = true; b = blk / NTILE1_; tile = blk % NTILE1_; }
  else { const int r = blk - 4 * NTILE1_; is1 = false; b = r / NTILE2_; tile = r % NTILE2_; }
  const int L = is1 ? L1_ : L2_;
  const int slotbase = is1 ? b * L1_ : N1_ + b * L2_;
  const float* feats = is1 ? feats1 + (size_t)b * L1_ * DM_ : feats2 + (size_t)b * L2_ * DM_;
  const float* pos = is1 ? pos1 + (size_t)b * L1_ * 3 : pos2 + (size_t)b * L2_ * 3;
  const MP P = is1 ? p2 : p1;       // s1 uses m2 params, s2 uses m1
  const bool rev = is1;             // s1 runs reversed
  const int t0 = tile * TA_;
  const int pstart = rev ? t0 : t0 - 3;   // halo side depends on direction

  __shared__ float hbuf[TAH_][DM_];   // 17920 B
  __shared__ float xcb[TAH_][DI_];    // 35840 B
  const int tid = threadIdx.x;

  // gather + positional embed
  {
    const int c = tid & 127;
    const int half = tid >> 7;
    const float pw0 = pe_w[c * 3 + 0], pw1 = pe_w[c * 3 + 1], pw2 = pe_w[c * 3 + 2];
    const float pb = pe_b[c];
    for (int lt = half; lt < TAH_; lt += 2) {
      const int p = pstart + lt;
      if (p >= 0 && p < L) {
        const int orig = o_all[slotbase + p];
        const float* fr = feats + (size_t)orig * DM_;
        const float* pr = pos + (size_t)orig * 3;
        hbuf[lt][c] = fr[c] + pr[0] * pw0 + pr[1] * pw1 + pr[2] * pw2 + pb;
      }
    }
  }
  __syncthreads();
  // LayerNorm (in place); invalid halo rows skipped (their xc_pre forced to 0)
  {
    const int lane = tid & 63, wv = tid >> 6;
    for (int lt = wv; lt < TAH_; lt += 4) {
      const int p = pstart + lt;
      if (p < 0 || p >= L) continue;
      float x0 = hbuf[lt][lane], x1 = hbuf[lt][lane + 64];
      float s = x0 + x1, q = x0 * x0 + x1 * x1;
      #pragma unroll
      for (int off = 32; off; off >>= 1) {
        s += __shfl_xor(s, off, 64);
        q += __shfl_xor(q, off, 64);
      }
      const float mu = s * (1.f / 128.f);
      const float rs = rsqrtf(q * (1.f / 128.f) - mu * mu + 1e-5f);
      hbuf[lt][lane]      = (x0 - mu) * rs * P.ln_g[lane]      + P.ln_b[lane];
      hbuf[lt][lane + 64] = (x1 - mu) * rs * P.ln_g[lane + 64] + P.ln_b[lane + 64];
    }
  }
  __syncthreads();
  // in_proj xc half (rows 0..255) for all 35 rows, into xcb
  {
    const int d = tid;
    const float* wrow = P.in_w + (size_t)d * DM_;
    #pragma unroll
    for (int g = 0; g < 2; ++g) {
      const int lt0 = g ? 18 : 0;
      const int ltn = g ? (TAH_ - 18) : 18;
      float acc[18];
      #pragma unroll
      for (int j = 0; j < 18; ++j) acc[j] = 0.f;
      for (int kc = 0; kc < DM_; kc += 16) {
        const float4 w0 = *(const float4*)(wrow + kc);
        const float4 w1 = *(const float4*)(wrow + kc + 4);
        const float4 w2 = *(const float4*)(wrow + kc + 8);
        const float4 w3 = *(const float4*)(wrow + kc + 12);
        #pragma unroll
        for (int j = 0; j < 18; ++j) {
          if (j < ltn) acc[j] += dot16f(&hbuf[lt0 + j][kc], w0, w1, w2, w3);
        }
      }
      #pragma unroll
      for (int j = 0; j < 18; ++j) {
        if (j < ltn) {
          const int lt = lt0 + j;
          const int p = pstart + lt;
          xcb[lt][d] = (p >= 0 && p < L) ? acc[j] : 0.f;  // zero-pad for conv
        }
      }
    }
  }
  // in_proj z half (rows 256..511), main tokens only, straight to global
  {
    const int d = tid;
    const float* wrow = P.in_w + (size_t)(DI_ + d) * DM_;
    const int lsh = rev ? 0 : 3;
    #pragma unroll
    for (int g = 0; g < 2; ++g) {
      float acc[16];
      #pragma unroll
      for (int j = 0; j < 16; ++j) acc[j] = 0.f;
      for (int kc = 0; kc < DM_; kc += 16) {
        const float4 w0 = *(const float4*)(wrow + kc);
        const float4 w1 = *(const float4*)(wrow + kc + 4);
        const float4 w2 = *(const float4*)(wrow + kc + 8);
        const float4 w3 = *(const float4*)(wrow + kc + 12);
        #pragma unroll
        for (int j = 0; j < 16; ++j)
          acc[j] += dot16f(&hbuf[g * 16 + j + lsh][kc], w0, w1, w2, w3);
      }
      #pragma unroll
      for (int j = 0; j < 16; ++j) {
        const int m = g * 16 + j;
        z_g[(size_t)(slotbase + t0 + m) * DI_ + d] = __float2bfloat16(acc[j]);
      }
    }
  }
  // depthwise causal conv (direction-flipped for rev) + bias + silu.
  // Column d of xcb is private to thread d -> no barrier needed.
  {
    const int d = tid;
    const float w0 = P.conv_w[d * 4 + 0], w1 = P.conv_w[d * 4 + 1],
                w2 = P.conv_w[d * 4 + 2], w3 = P.conv_w[d * 4 + 3];
    const float cb = P.conv_b[d];
    float xcv[TA_];
    #pragma unroll
    for (int m = 0; m < TA_; ++m) {
      float v;
      if (rev) v = w3 * xcb[m][d] + w2 * xcb[m + 1][d] + w1 * xcb[m + 2][d] + w0 * xcb[m + 3][d];
      else     v = w0 * xcb[m][d] + w1 * xcb[m + 1][d] + w2 * xcb[m + 2][d] + w3 * xcb[m + 3][d];
      v += cb;
      v = v * (1.f / (1.f + __expf(-v)));   // silu
      xcv[m] = v;
      xc_g[(size_t)(slotbase + t0 + m) * DI_ + d] = __float2bfloat16(v);
    }
    #pragma unroll
    for (int m = 0; m < TA_; ++m) xcb[m][d] = xcv[m];  // rows 0..31 now hold xc
  }
  __syncthreads();
  // x_proj: dbl[m][r] = xc[m] . xproj_w[r]
  {
    const int lane = tid & 63, wv = tid >> 6;
    if (lane < 40) {
      const float* wrow = P.xproj_w + (size_t)lane * DI_;
      for (int m = wv; m < TA_; m += 4) {
        float acc = 0.f;
        for (int k = 0; k < DI_; k += 16) {
          const float4 wa = *(const float4*)(wrow + k);
          const float4 wb = *(const float4*)(wrow + k + 4);
          const float4 wc = *(const float4*)(wrow + k + 8);
          const float4 wd = *(const float4*)(wrow + k + 12);
          acc += dot16f(&xcb[m][k], wa, wb, wc, wd);
        }
        dbl_g[(size_t)(slotbase + t0 + m) * 40 + lane] = acc;
      }
    }
  }
}

// ---------------------------------------------------------------------------
// Scan pass 1: per-chunk local state (h0=0) + sum(dt). 1 block per chunk, d=tid.
// ---------------------------------------------------------------------------
__global__ __launch_bounds__(256) void k_scan1(
    MP p1, MP p2,
    const __hip_bfloat16* __restrict__ xc_g, const float* __restrict__ dbl_g,
    float* __restrict__ hloc, float* __restrict__ sumdt_g)
{
  const int blk = blockIdx.x;
  bool is1; int b, pc;
  if (blk < 4 * NCH1_) { is1 = true; b = blk / NCH1_; pc = blk % NCH1_; }
  else { const int r = blk - 4 * NCH1_; is1 = false; b = r / NCH2_; pc = r % NCH2_; }
  const MP P = is1 ? p2 : p1;
  const int L = is1 ? L1_ : L2_;
  const bool rev = is1;
  const int slotbase = is1 ? b * L1_ : N1_ + b * L2_;
  const int d = threadIdx.x;
  float A[DS_];
  #pragma unroll
  for (int s = 0; s < DS_; ++s) A[s] = -__expf(P.A_log[d * DS_ + s]);
  float dtw[DTR_];
  #pragma unroll
  for (int r = 0; r < DTR_; ++r) dtw[r] = P.dtproj_w[d * DTR_ + r];
  const float dtb = P.dtproj_b[d];
  float h[DS_];
  #pragma unroll
  for (int s = 0; s < DS_; ++s) h[s] = 0.f;
  float sdt = 0.f;
  const int s0 = rev ? (L - (pc + 1) * TS_) : pc * TS_;
  for (int i = 0; i < TS_; ++i) {
    const int p = rev ? (s0 + TS_ - 1 - i) : (s0 + i);
    const size_t slot = (size_t)(slotbase + p);
    const float* dr = dbl_g + slot * 40;
    const float4 q0 = *(const float4*)(dr);
    const float4 q1 = *(const float4*)(dr + 4);
    const float dtraw = dtb + q0.x*dtw[0] + q0.y*dtw[1] + q0.z*dtw[2] + q0.w*dtw[3]
                            + q1.x*dtw[4] + q1.y*dtw[5] + q1.z*dtw[6] + q1.w*dtw[7];
    const float dt = softplusf(dtraw);
    const float u = __bfloat162float(xc_g[slot * DI_ + d]);
    const float du = dt * u;
    sdt += dt;
    float Bv[16];
    *(float4*)&Bv[0]  = *(const float4*)(dr + 8);
    *(float4*)&Bv[4]  = *(const float4*)(dr + 12);
    *(float4*)&Bv[8]  = *(const float4*)(dr + 16);
    *(float4*)&Bv[12] = *(const float4*)(dr + 20);
    #pragma unroll
    for (int s = 0; s < DS_; ++s) {
      const float a = __expf(dt * A[s]);
      h[s] = a * h[s] + du * Bv[s];
    }
  }
  float* hl = hloc + (size_t)blk * DS_ * DI_;
  #pragma unroll
  for (int s = 0; s < DS_; ++s) hl[s * DI_ + d] = h[s];
  sumdt_g[(size_t)blk * DI_ + d] = sdt;
}

// ---------------------------------------------------------------------------
// Scan pass 2: chain chunks. h_out = exp(A*sumdt)*h_in + h_local. 128 blocks.
// ---------------------------------------------------------------------------
__global__ __launch_bounds__(256) void k_scan2(
    MP p1, MP p2, const float* __restrict__ hloc,
    const float* __restrict__ sumdt_g, float* __restrict__ hin)
{
  const int seq = blockIdx.x >> 4;
  const int s = blockIdx.x & 15;
  const bool is1 = seq < 4;
  const int b = is1 ? seq : seq - 4;
  const MP P = is1 ? p2 : p1;
  const int nch = is1 ? NCH1_ : NCH2_;
  const int chbase = is1 ? b * NCH1_ : 4 * NCH1_ + b * NCH2_;
  const int d = threadIdx.x;
  const float A = -__expf(P.A_log[d * DS_ + s]);
  float carry = 0.f;
  for (int pc = 0; pc < nch; ++pc) {
    const size_t idx = (size_t)(chbase + pc);
    const float sdt = sumdt_g[idx * DI_ + d];
    hin[idx * DS_ * DI_ + s * DI_ + d] = carry;   // state entering chunk pc
    carry = __expf(A * sdt) * carry + hloc[idx * DS_ * DI_ + s * DI_ + d];
  }
}

// ---------------------------------------------------------------------------
// Scan pass 3: replay chunk from h_in, emit y (bf16).
// ---------------------------------------------------------------------------
__global__ __launch_bounds__(256) void k_scan3(
    MP p1, MP p2,
    const __hip_bfloat16* __restrict__ xc_g, const float* __restrict__ dbl_g,
    const float* __restrict__ hin, __hip_bfloat16* __restrict__ y_g)
{
  const int blk = blockIdx.x;
  bool is1; int b, pc;
  if (blk < 4 * NCH1_) { is1 = true; b = blk / NCH1_; pc = blk % NCH1_; }
  else { const int r = blk - 4 * NCH1_; is1 = false; b = r / NCH2_; pc = r % NCH2_; }
  const MP P = is1 ? p2 : p1;
  const int L = is1 ? L1_ : L2_;
  const bool rev = is1;
  const int slotbase = is1 ? b * L1_ : N1_ + b * L2_;
  const int d = threadIdx.x;
  float A[DS_];
  #pragma unroll
  for (int s = 0; s < DS_; ++s) A[s] = -__expf(P.A_log[d * DS_ + s]);
  float dtw[DTR_];
  #pragma unroll
  for (int r = 0; r < DTR_; ++r) dtw[r] = P.dtproj_w[d * DTR_ + r];
  const float dtb = P.dtproj_b[d];
  float h[DS_];
  const float* hi = hin + (size_t)blk * DS_ * DI_;
  #pragma unroll
  for (int s = 0; s < DS_; ++s) h[s] = hi[s * DI_ + d];
  const int s0 = rev ? (L - (pc + 1) * TS_) : pc * TS_;
  for (int i = 0; i < TS_; ++i) {
    const int p = rev ? (s0 + TS_ - 1 - i) : (s0 + i);
    const size_t slot = (size_t)(slotbase + p);
    const float* dr = dbl_g + slot * 40;
    const float4 q0 = *(const float4*)(dr);
    const float4 q1 = *(const float4*)(dr + 4);
    const float dtraw = dtb + q0.x*dtw[0] + q0.y*dtw[1] + q0.z*dtw[2] + q0.w*dtw[3]
                            + q1.x*dtw[4] + q1.y*dtw[5] + q1.z*dtw[6] + q1.w*dtw[7];
    const float dt = softplusf(dtraw);
    const float u = __bfloat162float(xc_g[slot * DI_ + d]);
    const float du = dt * u;
    float Bv[16], Cv[16];
    *(float4*)&Bv[0]  = *(const float4*)(dr + 8);
    *(float4*)&Bv[4]  = *(const float4*)(dr + 12);
    *(float4*)&Bv[8]  = *(const float4*)(dr + 16);
    *(float4*)&Bv[12] = *(const float4*)(dr + 20);
    *(float4*)&Cv[0]  = *(const float4*)(dr + 24);
    *(float4*)&Cv[4]  = *(const float4*)(dr + 28);
    *(float4*)&Cv[8]  = *(const float4*)(dr + 32);
    *(float4*)&Cv[12] = *(const float4*)(dr + 36);
    float y = 0.f;
    #pragma unroll
    for (int s = 0; s < DS_; ++s) {
      const float a = __expf(dt * A[s]);
      h[s] = a * h[s] + du * Bv[s];
      y += h[s] * Cv[s];
    }
    y_g[slot * DI_ + d] = __float2bfloat16(y);
  }
}

// ---------------------------------------------------------------------------
// Final: v = (y + xc*D)*silu(z); out_proj 256->128; output LN; scatter via perm.
// ---------------------------------------------------------------------------
__global__ __launch_bounds__(256) void k_final(
    MP p1, MP p2,
    const __hip_bfloat16* __restrict__ y_g, const __hip_bfloat16* __restrict__ xc_g,
    const __hip_bfloat16* __restrict__ z_g, const int* __restrict__ o_all,
    const float* __restrict__ norm_g, const float* __restrict__ norm_b,
    const float* __restrict__ normb_g, const float* __restrict__ normb_b,
    float* __restrict__ out)
{
  const int blk = blockIdx.x;
  bool is1; int b, tile;
  if (blk < 4 * NTILE1_) { is1 = true; b = blk / NTILE1_; tile = blk % NTILE1_; }
  else { const int r = blk - 4 * NTILE1_; is1 = false; b = r / NTILE2_; tile = r % NTILE2_; }
  const MP P = is1 ? p2 : p1;
  const float* gg = is1 ? normb_g : norm_g;
  const float* gb = is1 ? normb_b : norm_b;
  const int slotbase = is1 ? b * L1_ : N1_ + b * L2_;
  const int outbase = slotbase;   // same layout for output rows
  const int t0 = tile * TA_;
  __shared__ float vbuf[TA_][DI_];   // 32 KB
  __shared__ float obuf[TA_][DM_];   // 16 KB
  const int tid = threadIdx.x;
  {
    const int d = tid;
    const float Dp = P.Dp[d];
    for (int m = 0; m < TA_; ++m) {
      const size_t slot = (size_t)(slotbase + t0 + m);
      const float y = __bfloat162float(y_g[slot * DI_ + d]);
      const float xcv = __bfloat162float(xc_g[slot * DI_ + d]);
      const float zv = __bfloat162float(z_g[slot * DI_ + d]);
      vbuf[m][d] = (y + xcv * Dp) * (zv / (1.f + __expf(-zv)));
    }
  }
  __syncthreads();
  {
    const int c = tid & 127;
    const int g = tid >> 7;
    const float* wrow = P.out_w + (size_t)c * DI_;
    float acc[16];
    #pragma unroll
    for (int j = 0; j < 16; ++j) acc[j] = 0.f;
    for (int kc = 0; kc < DI_; kc += 16) {
      const float4 w0 = *(const float4*)(wrow + kc);
      const float4 w1 = *(const float4*)(wrow + kc + 4);
      const float4 w2 = *(const float4*)(wrow + kc + 8);
      const float4 w3 = *(const float4*)(wrow + kc + 12);
      #pragma unroll
      for (int j = 0; j < 16; ++j)
        acc[j] += dot16f(&vbuf[g * 16 + j][kc], w0, w1, w2, w3);
    }
    #pragma unroll
    for (int j = 0; j < 16; ++j) obuf[g * 16 + j][c] = acc[j];
  }
  __syncthreads();
  {
    const int lane = tid & 63, wv = tid >> 6;
    for (int m = wv; m < TA_; m += 4) {
      float x0 = obuf[m][lane], x1 = obuf[m][lane + 64];
      float s = x0 + x1, q = x0 * x0 + x1 * x1;
      #pragma unroll
      for (int off = 32; off; off >>= 1) {
        s += __shfl_xor(s, off, 64);
        q += __shfl_xor(q, off, 64);
      }
      const float mu = s * (1.f / 128.f);
      const float rs = rsqrtf(q * (1.f / 128.f) - mu * mu + 1e-5f);
      const int orig = o_all[slotbase + t0 + m];
      float* orow = out + (size_t)(outbase + orig) * DM_;
      orow[lane]      = (x0 - mu) * rs * gg[lane]      + gb[lane];
      orow[lane + 64] = (x1 - mu) * rs * gg[lane + 64] + gb[lane + 64];
    }
  }
}

// ---------------------------------------------------------------------------
extern "C" void kernel_launch(void* const* d_in, const int* in_sizes, int n_in,
                              void* d_out, int out_size, void* d_ws, size_t ws_size,
                              hipStream_t stream)
{
  (void)in_sizes; (void)n_in; (void)out_size; (void)ws_size;
  const float* feats1 = (const float*)d_in[0];
  const float* feats2 = (const float*)d_in[1];
  const float* pos1   = (const float*)d_in[2];
  const float* pos2   = (const float*)d_in[3];
  const int*   hil1   = (const int*)d_in[4];
  const int*   hil2   = (const int*)d_in[5];
  const float* pe_w   = (const float*)d_in[6];
  const float* pe_b   = (const float*)d_in[7];
  const float* norm_g  = (const float*)d_in[8];
  const float* norm_b  = (const float*)d_in[9];
  const float* normb_g = (const float*)d_in[10];
  const float* normb_b = (const float*)d_in[11];
  MP p1 { (const float*)d_in[12], (const float*)d_in[13], (const float*)d_in[14],
          (const float*)d_in[15], (const float*)d_in[16], (const float*)d_in[17],
          (const float*)d_in[18], (const float*)d_in[19], (const float*)d_in[20],
          (const float*)d_in[21], (const float*)d_in[22] };
  MP p2 { (const float*)d_in[23], (const float*)d_in[24], (const float*)d_in[25],
          (const float*)d_in[26], (const float*)d_in[27], (const float*)d_in[28],
          (const float*)d_in[29], (const float*)d_in[30], (const float*)d_in[31],
          (const float*)d_in[32], (const float*)d_in[33] };

  char* w = (char*)d_ws;
  auto take = [&](size_t bytes) -> char* {
    char* p = w; w += (bytes + 255) & ~(size_t)255; return p;
  };
  int* o_all = (int*)take((size_t)TOT_ * 4);
  unsigned* kA = (unsigned*)take((size_t)TOT_ * 4);
  int* iA = (int*)take((size_t)TOT_ * 4);
  unsigned* kB = (unsigned*)take((size_t)TOT_ * 4);
  int* iB = (int*)take((size_t)TOT_ * 4);
  __hip_bfloat16* xc = (__hip_bfloat16*)take((size_t)TOT_ * DI_ * 2);
  __hip_bfloat16* zb = (__hip_bfloat16*)take((size_t)TOT_ * DI_ * 2);
  __hip_bfloat16* yb = (__hip_bfloat16*)take((size_t)TOT_ * DI_ * 2);
  float* dbl = (float*)take((size_t)TOT_ * 40 * 4);
  float* hloc = (float*)take((size_t)NCHUNKS_ * DS_ * DI_ * 4);
  float* hin  = (float*)take((size_t)NCHUNKS_ * DS_ * DI_ * 4);
  float* sdt  = (float*)take((size_t)NCHUNKS_ * DI_ * 4);

  hipLaunchKernelGGL(k_sort, dim3(8), dim3(512), 0, stream,
                     hil1, hil2, o_all, kA, iA, kB, iB);
  hipLaunchKernelGGL(k_phaseA, dim3(NTILES_), dim3(256), 0, stream,
                     feats1, feats2, pos1, pos2, pe_w, pe_b, p1, p2, o_all, xc, zb, dbl);
  hipLaunchKernelGGL(k_scan1, dim3(NCHUNKS_), dim3(256), 0, stream,
                     p1, p2, xc, dbl, hloc, sdt);
  hipLaunchKernelGGL(k_scan2, dim3(128), dim3(256), 0, stream,
                     p1, p2, hloc, sdt, hin);
  hipLaunchKernelGGL(k_scan3, dim3(NCHUNKS_), dim3(256), 0, stream,
                     p1, p2, xc, dbl, hin, yb);
  hipLaunchKernelGGL(k_final, dim3(NTILES_), dim3(256), 0, stream,
                     p1, p2, yb, xc, zb, o_all, norm_g, norm_b, normb_g, normb_b,
                     (float*)d_out);
}

// Round 2
// 1927.706 us; speedup vs baseline: 1.8995x; 1.8995x over previous
//
#include <hip/hip_runtime.h>
#include <hip/hip_bf16.h>

#define DEV __device__ __forceinline__

constexpr int BATCH_ = 4;
constexpr int N1_ = 131072;
constexpr int N2_ = 32768;
constexpr int L1_ = N1_ / BATCH_;   // 32768
constexpr int L2_ = N2_ / BATCH_;   // 8192
constexpr int DM_ = 128;
constexpr int DI_ = 256;
constexpr int DS_ = 16;
constexpr int DTR_ = 8;
constexpr int TOT_ = N1_ + N2_;     // 163840

constexpr int TA_ = 32;             // phase A / final tile (tokens)
constexpr int TAH_ = TA_ + 3;       // + conv halo
constexpr int NTILE1_ = L1_ / TA_;  // 1024
constexpr int NTILE2_ = L2_ / TA_;  // 256
constexpr int NTILES_ = 4 * NTILE1_ + 4 * NTILE2_;  // 5120

constexpr int TS_ = 128;            // scan chunk length
constexpr int NCH1_ = L1_ / TS_;    // 256
constexpr int NCH2_ = L2_ / TS_;    // 64
constexpr int NCHUNKS_ = 4 * NCH1_ + 4 * NCH2_;     // 1280

// bf16 weight arena offsets (elements)
constexpr int IN1_OFF = 0;          // in_w model1 [512][128]
constexpr int IN2_OFF = 65536;
constexpr int XP1_OFF = 131072;     // xproj padded [48][256]
constexpr int XP2_OFF = 143360;
constexpr int OW1_OFF = 155648;     // out_w [128][256]
constexpr int OW2_OFF = 188416;
constexpr int W16_TOT = 221184;

typedef short short8 __attribute__((ext_vector_type(8)));
typedef float f32x4 __attribute__((ext_vector_type(4)));

struct MP {
  const float* ln_g; const float* ln_b; const float* in_w;
  const float* conv_w; const float* conv_b; const float* xproj_w;
  const float* dtproj_w; const float* dtproj_b; const float* A_log;
  const float* Dp; const float* out_w;
};

DEV float softplusf(float x) {
  return fmaxf(x, 0.f) + log1pf(__expf(-fabsf(x)));
}

DEV unsigned short f2bf(float f) {
  unsigned u = __builtin_bit_cast(unsigned, f);
  u += 0x7fffu + ((u >> 16) & 1u);
  return (unsigned short)(u >> 16);
}
DEV float bf2f(unsigned short s) {
  unsigned u = ((unsigned)s) << 16;
  return __builtin_bit_cast(float, u);
}

// ---------------------------------------------------------------------------
// Weight prep: fp32 -> bf16 copies (xproj padded 40->48 rows with zeros).
// ---------------------------------------------------------------------------
__global__ __launch_bounds__(256) void k_prep(
    const float* __restrict__ in_w1, const float* __restrict__ xp1,
    const float* __restrict__ ow1,
    const float* __restrict__ in_w2, const float* __restrict__ xp2,
    const float* __restrict__ ow2,
    unsigned short* __restrict__ w16)
{
  const int i = blockIdx.x * 256 + threadIdx.x;
  if (i >= W16_TOT) return;
  float v;
  if (i < IN2_OFF) v = in_w1[i - IN1_OFF];
  else if (i < XP1_OFF) v = in_w2[i - IN2_OFF];
  else if (i < XP2_OFF) {
    const int j = i - XP1_OFF; const int r = j >> 8;
    v = (r < 40) ? xp1[j] : 0.f;
  } else if (i < OW1_OFF) {
    const int j = i - XP2_OFF; const int r = j >> 8;
    v = (r < 40) ? xp2[j] : 0.f;
  } else if (i < OW2_OFF) v = ow1[i - OW1_OFF];
  else v = ow2[i - OW2_OFF];
  w16[i] = f2bf(v);
}

// ---------------------------------------------------------------------------
// Stable per-segment argsort: LSD radix, 4-bit digits, 8 passes. 1 block/segment.
// ---------------------------------------------------------------------------
__global__ __launch_bounds__(512) void k_sort(
    const int* __restrict__ hil1, const int* __restrict__ hil2,
    int* __restrict__ o_all,
    unsigned* __restrict__ kA, int* __restrict__ iA,
    unsigned* __restrict__ kB, int* __restrict__ iB)
{
  const int seg = blockIdx.x;
  int n, slotbase; const int* src;
  if (seg < 4) { n = L1_; src = hil1 + seg * L1_; slotbase = seg * L1_; }
  else { n = L2_; src = hil2 + (seg - 4) * L2_; slotbase = N1_ + (seg - 4) * L2_; }
  unsigned* keyA = kA + slotbase; int* idxA = iA + slotbase;
  unsigned* keyB = kB + slotbase; int* idxB = iB + slotbase;
  const int tid = threadIdx.x;
  const int C = n >> 9;
  __shared__ unsigned cnt[16 * 512];
  __shared__ unsigned wsum[8];
  for (int pass = 0; pass < 8; ++pass) {
    const int shift = pass * 4;
    #pragma unroll
    for (int d = 0; d < 16; ++d) cnt[d * 512 + tid] = 0;
    __syncthreads();
    const unsigned* ksrc = (pass & 1) ? keyB : keyA;
    const int* isrc = (pass & 1) ? idxB : idxA;
    if (pass == 0) {
      for (int j = 0; j < C; ++j) {
        unsigned k = (unsigned)src[tid * C + j];
        cnt[((k >> shift) & 15u) * 512 + tid]++;
      }
    } else {
      for (int j = 0; j < C; ++j) {
        unsigned k = ksrc[tid * C + j];
        cnt[((k >> shift) & 15u) * 512 + tid]++;
      }
    }
    __syncthreads();
    unsigned loc[16]; unsigned tot = 0;
    #pragma unroll
    for (int j = 0; j < 16; ++j) { loc[j] = tot; tot += cnt[tid * 16 + j]; }
    const int lane = tid & 63, wv = tid >> 6;
    unsigned inc = tot;
    #pragma unroll
    for (int off = 1; off < 64; off <<= 1) {
      unsigned v = (unsigned)__shfl_up((int)inc, off, 64);
      if (lane >= off) inc += v;
    }
    if (lane == 63) wsum[wv] = inc;
    __syncthreads();
    unsigned wbase = 0;
    for (int w2 = 0; w2 < 8; ++w2) if (w2 < wv) wbase += wsum[w2];
    const unsigned excl = wbase + inc - tot;
    #pragma unroll
    for (int j = 0; j < 16; ++j) cnt[tid * 16 + j] = excl + loc[j];
    __syncthreads();
    unsigned mybase[16];
    #pragma unroll
    for (int d = 0; d < 16; ++d) mybase[d] = cnt[d * 512 + tid];
    unsigned* kdst = (pass & 1) ? keyA : keyB;
    int* idst = (pass & 1) ? idxA : idxB;
    if (pass == 0) {
      for (int j = 0; j < C; ++j) {
        const int i = tid * C + j;
        const unsigned k = (unsigned)src[i];
        const unsigned d = (k >> shift) & 15u;
        const unsigned pos = mybase[d]++;
        kdst[pos] = k; idst[pos] = i;
      }
    } else {
      for (int j = 0; j < C; ++j) {
        const int i = tid * C + j;
        const unsigned k = ksrc[i];
        const unsigned d = (k >> shift) & 15u;
        const unsigned pos = mybase[d]++;
        kdst[pos] = k; idst[pos] = isrc[i];
      }
    }
    __syncthreads();
  }
  for (int j = 0; j < C; ++j) {
    const int i = tid * C + j;
    o_all[slotbase + i] = idxA[i];
  }
}

// ---------------------------------------------------------------------------
// Phase A: gather+embed -> LN -> in_proj (MFMA) -> conv+silu -> x_proj (MFMA)
// LDS arena (50016 B): xcb16[35][264] u16 | hfp[35][132] f32 (xc16 overlays) |
//                      hb16[48][136] u16
// ---------------------------------------------------------------------------
constexpr int HF_ = 132;    // hfp fp32 stride
constexpr int HB_ = 136;    // hb16 ushort stride
constexpr int XB_ = 264;    // xcb16 / xc16 ushort stride
constexpr int OFF_HFP = 18480;
constexpr int OFF_HB16 = 36960;
constexpr int SMEM_A = 50016;

__global__ __launch_bounds__(256) void k_phaseA(
    const float* __restrict__ feats1, const float* __restrict__ feats2,
    const float* __restrict__ pos1, const float* __restrict__ pos2,
    const float* __restrict__ pe_w, const float* __restrict__ pe_b,
    MP p1, MP p2, const int* __restrict__ o_all,
    const unsigned short* __restrict__ w16,
    __hip_bfloat16* __restrict__ xc_g, __hip_bfloat16* __restrict__ z_g,
    float* __restrict__ dbl_g)
{
  const int blk = blockIdx.x;
  bool is1; int b, tile;
  if (blk < 4 * NTILE1_) { is1 = true; b = blk / NTILE1_; tile = blk % NTILE1_; }
  else { const int r = blk - 4 * NTILE1_; is1 = false; b = r / NTILE2_; tile = r % NTILE2_; }
  const int L = is1 ? L1_ : L2_;
  const int slotbase = is1 ? b * L1_ : N1_ + b * L2_;
  const float* feats = is1 ? feats1 + (size_t)b * L1_ * DM_ : feats2 + (size_t)b * L2_ * DM_;
  const float* pos = is1 ? pos1 + (size_t)b * L1_ * 3 : pos2 + (size_t)b * L2_ * 3;
  const MP P = is1 ? p2 : p1;       // s1 uses m2 params, s2 uses m1
  const unsigned short* iw16 = w16 + (is1 ? IN2_OFF : IN1_OFF);
  const unsigned short* xp16 = w16 + (is1 ? XP2_OFF : XP1_OFF);
  const bool rev = is1;             // s1 runs reversed
  const int t0 = tile * TA_;
  const int pstart = rev ? t0 : t0 - 3;
  const int lsh = rev ? 0 : 3;

  __shared__ char smem[SMEM_A];
  unsigned short* xcb16 = (unsigned short*)smem;              // [35][264]
  float* hfp = (float*)(smem + OFF_HFP);                      // [35][132]
  unsigned short* xc16 = (unsigned short*)(smem + OFF_HFP);   // [32][264] (later)
  unsigned short* hb16 = (unsigned short*)(smem + OFF_HB16);  // [48][136]

  const int tid = threadIdx.x;
  const int lane = tid & 63, wv = tid >> 6;
  const int l15 = lane & 15, quad = lane >> 4;

  // P0: zero hb16 + gather + positional embed into hfp
  {
    unsigned* hz = (unsigned*)hb16;
    for (int i = tid; i < 48 * HB_ / 2; i += 256) hz[i] = 0;
    const int c = tid & 127;
    const int half = tid >> 7;
    const float pw0 = pe_w[c * 3 + 0], pw1 = pe_w[c * 3 + 1], pw2 = pe_w[c * 3 + 2];
    const float pb = pe_b[c];
    for (int lt = half; lt < TAH_; lt += 2) {
      const int p = pstart + lt;
      if (p >= 0 && p < L) {
        const int orig = o_all[slotbase + p];
        const float* fr = feats + (size_t)orig * DM_;
        const float* pr = pos + (size_t)orig * 3;
        hfp[lt * HF_ + c] = fr[c] + pr[0] * pw0 + pr[1] * pw1 + pr[2] * pw2 + pb;
      }
    }
  }
  __syncthreads();
  // P1: LayerNorm -> hb16 (bf16); invalid rows stay zero
  {
    for (int lt = wv; lt < TAH_; lt += 4) {
      const int p = pstart + lt;
      if (p < 0 || p >= L) continue;
      float x0 = hfp[lt * HF_ + lane], x1 = hfp[lt * HF_ + lane + 64];
      float s = x0 + x1, q = x0 * x0 + x1 * x1;
      #pragma unroll
      for (int off = 32; off; off >>= 1) {
        s += __shfl_xor(s, off, 64);
        q += __shfl_xor(q, off, 64);
      }
      const float mu = s * (1.f / 128.f);
      const float rs = rsqrtf(q * (1.f / 128.f) - mu * mu + 1e-5f);
      hb16[lt * HB_ + lane]      = f2bf((x0 - mu) * rs * P.ln_g[lane]      + P.ln_b[lane]);
      hb16[lt * HB_ + lane + 64] = f2bf((x1 - mu) * rs * P.ln_g[lane + 64] + P.ln_b[lane + 64]);
    }
  }
  __syncthreads();
  // P2: in_proj via MFMA. C[48x512] = hb16[48x128] @ in_w^T. Wave w: n-tiles nn*4+w.
  {
    short8 afr[3][4];
    #pragma unroll
    for (int mt = 0; mt < 3; ++mt)
      #pragma unroll
      for (int t = 0; t < 4; ++t)
        afr[mt][t] = *(const short8*)(hb16 + (mt * 16 + l15) * HB_ + t * 32 + quad * 8);
    for (int nn = 0; nn < 8; ++nn) {
      const int ntile = nn * 4 + wv;
      f32x4 acc[3];
      #pragma unroll
      for (int mt = 0; mt < 3; ++mt) acc[mt] = (f32x4){0.f, 0.f, 0.f, 0.f};
      #pragma unroll
      for (int t = 0; t < 4; ++t) {
        const short8 bfr = *(const short8*)(iw16 + (size_t)(ntile * 16 + l15) * DM_ + t * 32 + quad * 8);
        #pragma unroll
        for (int mt = 0; mt < 3; ++mt)
          acc[mt] = __builtin_amdgcn_mfma_f32_16x16x32_bf16(afr[mt][t], bfr, acc[mt], 0, 0, 0);
      }
      const int col = ntile * 16 + l15;
      if (col < 256) {
        #pragma unroll
        for (int mt = 0; mt < 3; ++mt)
          #pragma unroll
          for (int r = 0; r < 4; ++r) {
            const int row = mt * 16 + quad * 4 + r;
            if (row < TAH_) xcb16[row * XB_ + col] = f2bf(acc[mt][r]);
          }
      } else {
        #pragma unroll
        for (int mt = 0; mt < 3; ++mt)
          #pragma unroll
          for (int r = 0; r < 4; ++r) {
            const int row = mt * 16 + quad * 4 + r;
            const int m = row - lsh;
            if (m >= 0 && m < TA_)
              z_g[(size_t)(slotbase + t0 + m) * DI_ + (col - 256)] = __float2bfloat16(acc[mt][r]);
          }
      }
    }
  }
  __syncthreads();
  // P3: depthwise causal conv (dir-flipped for rev) + bias + silu -> xc_g + xc16
  {
    const int d = tid;
    const float w0 = P.conv_w[d * 4 + 0], w1 = P.conv_w[d * 4 + 1],
                w2 = P.conv_w[d * 4 + 2], w3 = P.conv_w[d * 4 + 3];
    const float cb = P.conv_b[d];
    float x0 = bf2f(xcb16[0 * XB_ + d]), x1 = bf2f(xcb16[1 * XB_ + d]),
          x2 = bf2f(xcb16[2 * XB_ + d]);
    unsigned short out16[TA_];
    #pragma unroll
    for (int m = 0; m < TA_; ++m) {
      const float x3 = bf2f(xcb16[(m + 3) * XB_ + d]);
      float v;
      if (rev) v = w3 * x0 + w2 * x1 + w1 * x2 + w0 * x3;
      else     v = w0 * x0 + w1 * x1 + w2 * x2 + w3 * x3;
      v += cb;
      v = v * (1.f / (1.f + __expf(-v)));
      const unsigned short vb = f2bf(v);
      out16[m] = vb;
      xc_g[(size_t)(slotbase + t0 + m) * DI_ + d] = __builtin_bit_cast(__hip_bfloat16, vb);
      x0 = x1; x1 = x2; x2 = x3;
    }
    __syncthreads();   // xc16 overlays hfp; all reads of xcb16 done per-thread-column
    #pragma unroll
    for (int m = 0; m < TA_; ++m) xc16[m * XB_ + d] = out16[m];
  }
  __syncthreads();
  // P4: x_proj via MFMA. dbl[32x40] = xc16[32x256] @ xproj_w^T. Waves 0-2.
  if (wv < 3) {
    f32x4 acc0 = (f32x4){0.f,0.f,0.f,0.f}, acc1 = acc0;
    #pragma unroll
    for (int t = 0; t < 8; ++t) {
      const short8 bfr = *(const short8*)(xp16 + (size_t)(wv * 16 + l15) * DI_ + t * 32 + quad * 8);
      const short8 a0 = *(const short8*)(xc16 + (l15) * XB_ + t * 32 + quad * 8);
      const short8 a1 = *(const short8*)(xc16 + (16 + l15) * XB_ + t * 32 + quad * 8);
      acc0 = __builtin_amdgcn_mfma_f32_16x16x32_bf16(a0, bfr, acc0, 0, 0, 0);
      acc1 = __builtin_amdgcn_mfma_f32_16x16x32_bf16(a1, bfr, acc1, 0, 0, 0);
    }
    const int col = wv * 16 + l15;
    if (col < 40) {
      #pragma unroll
      for (int r = 0; r < 4; ++r) {
        dbl_g[(size_t)(slotbase + t0 + quad * 4 + r) * 40 + col] = acc0[r];
        dbl_g[(size_t)(slotbase + t0 + 16 + quad * 4 + r) * 40 + col] = acc1[r];
      }
    }
  }
}

// ---------------------------------------------------------------------------
// Scan pass 1: per-chunk local state (h0=0) + sum(dt). 1 block per chunk, d=tid.
// ---------------------------------------------------------------------------
__global__ __launch_bounds__(256) void k_scan1(
    MP p1, MP p2,
    const __hip_bfloat16* __restrict__ xc_g, const float* __restrict__ dbl_g,
    float* __restrict__ hloc, float* __restrict__ sumdt_g)
{
  const int blk = blockIdx.x;
  bool is1; int b, pc;
  if (blk < 4 * NCH1_) { is1 = true; b = blk / NCH1_; pc = blk % NCH1_; }
  else { const int r = blk - 4 * NCH1_; is1 = false; b = r / NCH2_; pc = r % NCH2_; }
  const MP P = is1 ? p2 : p1;
  const int L = is1 ? L1_ : L2_;
  const bool rev = is1;
  const int slotbase = is1 ? b * L1_ : N1_ + b * L2_;
  const int d = threadIdx.x;
  float A[DS_];
  #pragma unroll
  for (int s = 0; s < DS_; ++s) A[s] = -__expf(P.A_log[d * DS_ + s]);
  float dtw[DTR_];
  #pragma unroll
  for (int r = 0; r < DTR_; ++r) dtw[r] = P.dtproj_w[d * DTR_ + r];
  const float dtb = P.dtproj_b[d];
  float h[DS_];
  #pragma unroll
  for (int s = 0; s < DS_; ++s) h[s] = 0.f;
  float sdt = 0.f;
  const int s0 = rev ? (L - (pc + 1) * TS_) : pc * TS_;
  for (int i = 0; i < TS_; ++i) {
    const int p = rev ? (s0 + TS_ - 1 - i) : (s0 + i);
    const size_t slot = (size_t)(slotbase + p);
    const float* dr = dbl_g + slot * 40;
    const float4 q0 = *(const float4*)(dr);
    const float4 q1 = *(const float4*)(dr + 4);
    const float dtraw = dtb + q0.x*dtw[0] + q0.y*dtw[1] + q0.z*dtw[2] + q0.w*dtw[3]
                            + q1.x*dtw[4] + q1.y*dtw[5] + q1.z*dtw[6] + q1.w*dtw[7];
    const float dt = softplusf(dtraw);
    const float u = __bfloat162float(xc_g[slot * DI_ + d]);
    const float du = dt * u;
    sdt += dt;
    float Bv[16];
    *(float4*)&Bv[0]  = *(const float4*)(dr + 8);
    *(float4*)&Bv[4]  = *(const float4*)(dr + 12);
    *(float4*)&Bv[8]  = *(const float4*)(dr + 16);
    *(float4*)&Bv[12] = *(const float4*)(dr + 20);
    #pragma unroll
    for (int s = 0; s < DS_; ++s) {
      const float a = __expf(dt * A[s]);
      h[s] = a * h[s] + du * Bv[s];
    }
  }
  float* hl = hloc + (size_t)blk * DS_ * DI_;
  #pragma unroll
  for (int s = 0; s < DS_; ++s) hl[s * DI_ + d] = h[s];
  sumdt_g[(size_t)blk * DI_ + d] = sdt;
}

// ---------------------------------------------------------------------------
// Scan pass 2: chain chunks. h_out = exp(A*sumdt)*h_in + h_local. 128 blocks.
// ---------------------------------------------------------------------------
__global__ __launch_bounds__(256) void k_scan2(
    MP p1, MP p2, const float* __restrict__ hloc,
    const float* __restrict__ sumdt_g, float* __restrict__ hin)
{
  const int seq = blockIdx.x >> 4;
  const int s = blockIdx.x & 15;
  const bool is1 = seq < 4;
  const int b = is1 ? seq : seq - 4;
  const MP P = is1 ? p2 : p1;
  const int nch = is1 ? NCH1_ : NCH2_;
  const int chbase = is1 ? b * NCH1_ : 4 * NCH1_ + b * NCH2_;
  const int d = threadIdx.x;
  const float A = -__expf(P.A_log[d * DS_ + s]);
  float carry = 0.f;
  for (int pc = 0; pc < nch; ++pc) {
    const size_t idx = (size_t)(chbase + pc);
    const float sdt = sumdt_g[idx * DI_ + d];
    hin[idx * DS_ * DI_ + s * DI_ + d] = carry;
    carry = __expf(A * sdt) * carry + hloc[idx * DS_ * DI_ + s * DI_ + d];
  }
}

// ---------------------------------------------------------------------------
// Scan pass 3: replay chunk from h_in, emit y (bf16).
// ---------------------------------------------------------------------------
__global__ __launch_bounds__(256) void k_scan3(
    MP p1, MP p2,
    const __hip_bfloat16* __restrict__ xc_g, const float* __restrict__ dbl_g,
    const float* __restrict__ hin, __hip_bfloat16* __restrict__ y_g)
{
  const int blk = blockIdx.x;
  bool is1; int b, pc;
  if (blk < 4 * NCH1_) { is1 = true; b = blk / NCH1_; pc = blk % NCH1_; }
  else { const int r = blk - 4 * NCH1_; is1 = false; b = r / NCH2_; pc = r % NCH2_; }
  const MP P = is1 ? p2 : p1;
  const int L = is1 ? L1_ : L2_;
  const bool rev = is1;
  const int slotbase = is1 ? b * L1_ : N1_ + b * L2_;
  const int d = threadIdx.x;
  float A[DS_];
  #pragma unroll
  for (int s = 0; s < DS_; ++s) A[s] = -__expf(P.A_log[d * DS_ + s]);
  float dtw[DTR_];
  #pragma unroll
  for (int r = 0; r < DTR_; ++r) dtw[r] = P.dtproj_w[d * DTR_ + r];
  const float dtb = P.dtproj_b[d];
  float h[DS_];
  const float* hi = hin + (size_t)blk * DS_ * DI_;
  #pragma unroll
  for (int s = 0; s < DS_; ++s) h[s] = hi[s * DI_ + d];
  const int s0 = rev ? (L - (pc + 1) * TS_) : pc * TS_;
  for (int i = 0; i < TS_; ++i) {
    const int p = rev ? (s0 + TS_ - 1 - i) : (s0 + i);
    const size_t slot = (size_t)(slotbase + p);
    const float* dr = dbl_g + slot * 40;
    const float4 q0 = *(const float4*)(dr);
    const float4 q1 = *(const float4*)(dr + 4);
    const float dtraw = dtb + q0.x*dtw[0] + q0.y*dtw[1] + q0.z*dtw[2] + q0.w*dtw[3]
                            + q1.x*dtw[4] + q1.y*dtw[5] + q1.z*dtw[6] + q1.w*dtw[7];
    const float dt = softplusf(dtraw);
    const float u = __bfloat162float(xc_g[slot * DI_ + d]);
    const float du = dt * u;
    float Bv[16], Cv[16];
    *(float4*)&Bv[0]  = *(const float4*)(dr + 8);
    *(float4*)&Bv[4]  = *(const float4*)(dr + 12);
    *(float4*)&Bv[8]  = *(const float4*)(dr + 16);
    *(float4*)&Bv[12] = *(const float4*)(dr + 20);
    *(float4*)&Cv[0]  = *(const float4*)(dr + 24);
    *(float4*)&Cv[4]  = *(const float4*)(dr + 28);
    *(float4*)&Cv[8]  = *(const float4*)(dr + 32);
    *(float4*)&Cv[12] = *(const float4*)(dr + 36);
    float y = 0.f;
    #pragma unroll
    for (int s = 0; s < DS_; ++s) {
      const float a = __expf(dt * A[s]);
      h[s] = a * h[s] + du * Bv[s];
      y += h[s] * Cv[s];
    }
    y_g[slot * DI_ + d] = __float2bfloat16(y);
  }
}

// ---------------------------------------------------------------------------
// Final: v = (y + xc*D)*silu(z); out_proj (MFMA); output LN; scatter via perm.
// ---------------------------------------------------------------------------
constexpr int OB_ = 132;
__global__ __launch_bounds__(256) void k_final(
    MP p1, MP p2,
    const __hip_bfloat16* __restrict__ y_g, const __hip_bfloat16* __restrict__ xc_g,
    const __hip_bfloat16* __restrict__ z_g, const int* __restrict__ o_all,
    const unsigned short* __restrict__ w16,
    const float* __restrict__ norm_g, const float* __restrict__ norm_b,
    const float* __restrict__ normb_g, const float* __restrict__ normb_b,
    float* __restrict__ out)
{
  const int blk = blockIdx.x;
  bool is1; int b, tile;
  if (blk < 4 * NTILE1_) { is1 = true; b = blk / NTILE1_; tile = blk % NTILE1_; }
  else { const int r = blk - 4 * NTILE1_; is1 = false; b = r / NTILE2_; tile = r % NTILE2_; }
  const MP P = is1 ? p2 : p1;
  const unsigned short* W = w16 + (is1 ? OW2_OFF : OW1_OFF);
  const float* gg = is1 ? normb_g : norm_g;
  const float* gb = is1 ? normb_b : norm_b;
  const int slotbase = is1 ? b * L1_ : N1_ + b * L2_;
  const int t0 = tile * TA_;
  __shared__ unsigned short v16[TA_ * XB_];  // 16896 B
  __shared__ float obuf[TA_ * OB_];          // 16896 B
  const int tid = threadIdx.x;
  const int lane = tid & 63, wv = tid >> 6;
  const int l15 = lane & 15, quad = lane >> 4;
  {
    const int d = tid;
    const float Dp = P.Dp[d];
    for (int m = 0; m < TA_; ++m) {
      const size_t slot = (size_t)(slotbase + t0 + m);
      const float y = __bfloat162float(y_g[slot * DI_ + d]);
      const float xcv = __bfloat162float(xc_g[slot * DI_ + d]);
      const float zv = __bfloat162float(z_g[slot * DI_ + d]);
      v16[m * XB_ + d] = f2bf((y + xcv * Dp) * (zv / (1.f + __expf(-zv))));
    }
  }
  __syncthreads();
  // out_proj MFMA: [32x128] = v16[32x256] @ out_w^T. Wave w: n-tiles w, w+4.
  for (int nn = 0; nn < 2; ++nn) {
    const int ntile = wv + nn * 4;
    f32x4 acc0 = (f32x4){0.f,0.f,0.f,0.f}, acc1 = acc0;
    #pragma unroll
    for (int t = 0; t < 8; ++t) {
      const short8 bfr = *(const short8*)(W + (size_t)(ntile * 16 + l15) * DI_ + t * 32 + quad * 8);
      const short8 a0 = *(const short8*)(v16 + (l15) * XB_ + t * 32 + quad * 8);
      const short8 a1 = *(const short8*)(v16 + (16 + l15) * XB_ + t * 32 + quad * 8);
      acc0 = __builtin_amdgcn_mfma_f32_16x16x32_bf16(a0, bfr, acc0, 0, 0, 0);
      acc1 = __builtin_amdgcn_mfma_f32_16x16x32_bf16(a1, bfr, acc1, 0, 0, 0);
    }
    const int col = ntile * 16 + l15;
    #pragma unroll
    for (int r = 0; r < 4; ++r) {
      obuf[(quad * 4 + r) * OB_ + col] = acc0[r];
      obuf[(16 + quad * 4 + r) * OB_ + col] = acc1[r];
    }
  }
  __syncthreads();
  {
    for (int m = wv; m < TA_; m += 4) {
      float x0 = obuf[m * OB_ + lane], x1 = obuf[m * OB_ + lane + 64];
      float s = x0 + x1, q = x0 * x0 + x1 * x1;
      #pragma unroll
      for (int off = 32; off; off >>= 1) {
        s += __shfl_xor(s, off, 64);
        q += __shfl_xor(q, off, 64);
      }
      const float mu = s * (1.f / 128.f);
      const float rs = rsqrtf(q * (1.f / 128.f) - mu * mu + 1e-5f);
      const int orig = o_all[slotbase + t0 + m];
      float* orow = out + (size_t)(slotbase + orig) * DM_;
      orow[lane]      = (x0 - mu) * rs * gg[lane]      + gb[lane];
      orow[lane + 64] = (x1 - mu) * rs * gg[lane + 64] + gb[lane + 64];
    }
  }
}

// ---------------------------------------------------------------------------
extern "C" void kernel_launch(void* const* d_in, const int* in_sizes, int n_in,
                              void* d_out, int out_size, void* d_ws, size_t ws_size,
                              hipStream_t stream)
{
  (void)in_sizes; (void)n_in; (void)out_size; (void)ws_size;
  const float* feats1 = (const float*)d_in[0];
  const float* feats2 = (const float*)d_in[1];
  const float* pos1   = (const float*)d_in[2];
  const float* pos2   = (const float*)d_in[3];
  const int*   hil1   = (const int*)d_in[4];
  const int*   hil2   = (const int*)d_in[5];
  const float* pe_w   = (const float*)d_in[6];
  const float* pe_b   = (const float*)d_in[7];
  const float* norm_g  = (const float*)d_in[8];
  const float* norm_b  = (const float*)d_in[9];
  const float* normb_g = (const float*)d_in[10];
  const float* normb_b = (const float*)d_in[11];
  MP p1 { (const float*)d_in[12], (const float*)d_in[13], (const float*)d_in[14],
          (const float*)d_in[15], (const float*)d_in[16], (const float*)d_in[17],
          (const float*)d_in[18], (const float*)d_in[19], (const float*)d_in[20],
          (const float*)d_in[21], (const float*)d_in[22] };
  MP p2 { (const float*)d_in[23], (const float*)d_in[24], (const float*)d_in[25],
          (const float*)d_in[26], (const float*)d_in[27], (const float*)d_in[28],
          (const float*)d_in[29], (const float*)d_in[30], (const float*)d_in[31],
          (const float*)d_in[32], (const float*)d_in[33] };

  char* w = (char*)d_ws;
  auto take = [&](size_t bytes) -> char* {
    char* p = w; w += (bytes + 255) & ~(size_t)255; return p;
  };
  int* o_all = (int*)take((size_t)TOT_ * 4);
  unsigned* kA = (unsigned*)take((size_t)TOT_ * 4);
  int* iA = (int*)take((size_t)TOT_ * 4);
  unsigned* kB = (unsigned*)take((size_t)TOT_ * 4);
  int* iB = (int*)take((size_t)TOT_ * 4);
  __hip_bfloat16* xc = (__hip_bfloat16*)take((size_t)TOT_ * DI_ * 2);
  __hip_bfloat16* zb = (__hip_bfloat16*)take((size_t)TOT_ * DI_ * 2);
  __hip_bfloat16* yb = (__hip_bfloat16*)take((size_t)TOT_ * DI_ * 2);
  float* dbl = (float*)take((size_t)TOT_ * 40 * 4);
  float* hloc = (float*)take((size_t)NCHUNKS_ * DS_ * DI_ * 4);
  float* hin  = (float*)take((size_t)NCHUNKS_ * DS_ * DI_ * 4);
  float* sdt  = (float*)take((size_t)NCHUNKS_ * DI_ * 4);
  unsigned short* w16 = (unsigned short*)take((size_t)W16_TOT * 2);

  hipLaunchKernelGGL(k_prep, dim3((W16_TOT + 255) / 256), dim3(256), 0, stream,
                     p1.in_w, p1.xproj_w, p1.out_w, p2.in_w, p2.xproj_w, p2.out_w, w16);
  hipLaunchKernelGGL(k_sort, dim3(8), dim3(512), 0, stream,
                     hil1, hil2, o_all, kA, iA, kB, iB);
  hipLaunchKernelGGL(k_phaseA, dim3(NTILES_), dim3(256), 0, stream,
                     feats1, feats2, pos1, pos2, pe_w, pe_b, p1, p2, o_all, w16,
                     xc, zb, dbl);
  hipLaunchKernelGGL(k_scan1, dim3(NCHUNKS_), dim3(256), 0, stream,
                     p1, p2, xc, dbl, hloc, sdt);
  hipLaunchKernelGGL(k_scan2, dim3(128), dim3(256), 0, stream,
                     p1, p2, hloc, sdt, hin);
  hipLaunchKernelGGL(k_scan3, dim3(NCHUNKS_), dim3(256), 0, stream,
                     p1, p2, xc, dbl, hin, yb);
  hipLaunchKernelGGL(k_final, dim3(NTILES_), dim3(256), 0, stream,
                     p1, p2, yb, xc, zb, o_all, w16, norm_g, norm_b, normb_g, normb_b,
                     (float*)d_out);
}

// Round 3
// 1328.452 us; speedup vs baseline: 2.7563x; 1.4511x over previous
//
#include <hip/hip_runtime.h>
#include <hip/hip_bf16.h>

#define DEV __device__ __forceinline__

constexpr int BATCH_ = 4;
constexpr int N1_ = 131072;
constexpr int N2_ = 32768;
constexpr int L1_ = N1_ / BATCH_;   // 32768
constexpr int L2_ = N2_ / BATCH_;   // 8192
constexpr int DM_ = 128;
constexpr int DI_ = 256;
constexpr int DS_ = 16;
constexpr int DTR_ = 8;
constexpr int TOT_ = N1_ + N2_;     // 163840

constexpr int TA_ = 32;             // phase A / final tile (tokens)
constexpr int TAH_ = TA_ + 3;       // + conv halo
constexpr int NTILE1_ = L1_ / TA_;  // 1024
constexpr int NTILE2_ = L2_ / TA_;  // 256
constexpr int NTILES_ = 4 * NTILE1_ + 4 * NTILE2_;  // 5120

constexpr int TS_ = 128;            // scan chunk length
constexpr int NCH1_ = L1_ / TS_;    // 256
constexpr int NCH2_ = L2_ / TS_;    // 64
constexpr int NCHUNKS_ = 4 * NCH1_ + 4 * NCH2_;     // 1280

// radix sort: 10-bit digits, 3 passes, 1024-elem tiles
constexpr int NST_ = 160;           // 4*32 + 4*8 sort tiles

// bf16 weight arena offsets (elements)
constexpr int IN1_OFF = 0;          // in_w model1 [512][128]
constexpr int IN2_OFF = 65536;
constexpr int XP1_OFF = 131072;     // xproj padded [48][256]
constexpr int XP2_OFF = 143360;
constexpr int OW1_OFF = 155648;     // out_w [128][256]
constexpr int OW2_OFF = 188416;
constexpr int W16_TOT = 221184;

typedef short short8 __attribute__((ext_vector_type(8)));
typedef float f32x4 __attribute__((ext_vector_type(4)));

struct MP {
  const float* ln_g; const float* ln_b; const float* in_w;
  const float* conv_w; const float* conv_b; const float* xproj_w;
  const float* dtproj_w; const float* dtproj_b; const float* A_log;
  const float* Dp; const float* out_w;
};

DEV float softplusf(float x) {
  return fmaxf(x, 0.f) + log1pf(__expf(-fabsf(x)));
}

DEV unsigned short f2bf(float f) {
  unsigned u = __builtin_bit_cast(unsigned, f);
  u += 0x7fffu + ((u >> 16) & 1u);
  return (unsigned short)(u >> 16);
}
DEV float bf2f(unsigned short s) {
  unsigned u = ((unsigned)s) << 16;
  return __builtin_bit_cast(float, u);
}

DEV void sort_tile_info(int tile, int& seg, int& tis, int& slotbase) {
  if (tile < 128) { seg = tile >> 5; tis = tile & 31; slotbase = seg * L1_; }
  else { seg = 4 + ((tile - 128) >> 3); tis = (tile - 128) & 7; slotbase = N1_ + (seg - 4) * L2_; }
}

// ---------------------------------------------------------------------------
// Weight prep: fp32 -> bf16 copies (xproj padded 40->48 rows with zeros).
// ---------------------------------------------------------------------------
__global__ __launch_bounds__(256) void k_prep(
    const float* __restrict__ in_w1, const float* __restrict__ xp1,
    const float* __restrict__ ow1,
    const float* __restrict__ in_w2, const float* __restrict__ xp2,
    const float* __restrict__ ow2,
    unsigned short* __restrict__ w16)
{
  const int i = blockIdx.x * 256 + threadIdx.x;
  if (i >= W16_TOT) return;
  float v;
  if (i < IN2_OFF) v = in_w1[i - IN1_OFF];
  else if (i < XP1_OFF) v = in_w2[i - IN2_OFF];
  else if (i < XP2_OFF) {
    const int j = i - XP1_OFF; const int r = j >> 8;
    v = (r < 40) ? xp1[j] : 0.f;
  } else if (i < OW1_OFF) {
    const int j = i - XP2_OFF; const int r = j >> 8;
    v = (r < 40) ? xp2[j] : 0.f;
  } else if (i < OW2_OFF) v = ow1[i - OW1_OFF];
  else v = ow2[i - OW2_OFF];
  w16[i] = f2bf(v);
}

// ---------------------------------------------------------------------------
// Radix sort pass kernels (stable, 10-bit digits).
// ---------------------------------------------------------------------------
__global__ __launch_bounds__(256) void k_hist(
    const int* __restrict__ hil1, const int* __restrict__ hil2,
    const unsigned* __restrict__ ksrc, unsigned* __restrict__ histg,
    int shift, int pass0)
{
  const int tile = blockIdx.x;
  int seg, tis, slotbase;
  sort_tile_info(tile, seg, tis, slotbase);
  const int tid = threadIdx.x;
  __shared__ unsigned h[1024];
  #pragma unroll
  for (int i = 0; i < 4; ++i) h[i * 256 + tid] = 0;
  __syncthreads();
  #pragma unroll
  for (int it = 0; it < 4; ++it) {
    const int li = tis * 1024 + it * 256 + tid;
    unsigned k;
    if (pass0) k = (unsigned)(seg < 4 ? hil1[seg * L1_ + li] : hil2[(seg - 4) * L2_ + li]);
    else       k = ksrc[slotbase + li];
    atomicAdd(&h[(k >> shift) & 1023u], 1u);
  }
  __syncthreads();
  #pragma unroll
  for (int i = 0; i < 4; ++i)
    histg[tile * 1024 + i * 256 + tid] = h[i * 256 + tid];
}

__global__ __launch_bounds__(256) void k_scanoff(
    const unsigned* __restrict__ histg, unsigned* __restrict__ offg)
{
  const int seg = blockIdx.x;
  const int ntiles = seg < 4 ? 32 : 8;
  const int tilebase = seg < 4 ? seg * 32 : 128 + (seg - 4) * 8;
  const int tid = threadIdx.x;
  const int d0 = tid * 4;
  unsigned tot[4] = {0, 0, 0, 0};
  for (int t = 0; t < ntiles; ++t) {
    const unsigned* hp = &histg[(size_t)(tilebase + t) * 1024 + d0];
    tot[0] += hp[0]; tot[1] += hp[1]; tot[2] += hp[2]; tot[3] += hp[3];
  }
  unsigned lp[4]; unsigned s = 0;
  #pragma unroll
  for (int j = 0; j < 4; ++j) { lp[j] = s; s += tot[j]; }
  const int lane = tid & 63, wv = tid >> 6;
  unsigned inc = s;
  #pragma unroll
  for (int off = 1; off < 64; off <<= 1) {
    unsigned v = (unsigned)__shfl_up((int)inc, off, 64);
    if (lane >= off) inc += v;
  }
  __shared__ unsigned wsum[4];
  if (lane == 63) wsum[wv] = inc;
  __syncthreads();
  unsigned wbase = 0;
  for (int w = 0; w < 4; ++w) if (w < wv) wbase += wsum[w];
  const unsigned base = wbase + inc - s;   // exclusive over threads
  #pragma unroll
  for (int j = 0; j < 4; ++j) {
    unsigned run = base + lp[j];
    for (int t = 0; t < ntiles; ++t) {
      offg[(size_t)(tilebase + t) * 1024 + d0 + j] = run;
      run += histg[(size_t)(tilebase + t) * 1024 + d0 + j];
    }
  }
}

__global__ __launch_bounds__(256) void k_scatter(
    const int* __restrict__ hil1, const int* __restrict__ hil2,
    const unsigned* __restrict__ ksrc, const int* __restrict__ isrc,
    const unsigned* __restrict__ offg,
    unsigned* __restrict__ kdst, int* __restrict__ idst,
    int* __restrict__ o_all, int shift, int pass0, int last)
{
  const int tile = blockIdx.x;
  int seg, tis, slotbase;
  sort_tile_info(tile, seg, tis, slotbase);
  const int tid = threadIdx.x;
  const int lane = tid & 63, wv = tid >> 6;
  __shared__ unsigned runb[1024];
  __shared__ unsigned wcnt[4 * 1024];
  #pragma unroll
  for (int i = 0; i < 4; ++i) runb[i * 256 + tid] = offg[(size_t)tile * 1024 + i * 256 + tid];
  #pragma unroll
  for (int it = 0; it < 4; ++it) {
    #pragma unroll
    for (int i = 0; i < 16; ++i) wcnt[i * 256 + tid] = 0;
    __syncthreads();
    const int li = tis * 1024 + it * 256 + tid;
    unsigned k; int v;
    if (pass0) {
      k = (unsigned)(seg < 4 ? hil1[seg * L1_ + li] : hil2[(seg - 4) * L2_ + li]);
      v = li;
    } else {
      k = ksrc[slotbase + li]; v = isrc[slotbase + li];
    }
    const unsigned d = (k >> shift) & 1023u;
    unsigned long long m = ~0ull;
    #pragma unroll
    for (int b = 0; b < 10; ++b) {
      const unsigned long long bb = __ballot((int)((d >> b) & 1u));
      m &= ((d >> b) & 1u) ? bb : ~bb;
    }
    const unsigned lrank = (unsigned)__popcll(m & ((1ull << lane) - 1ull));
    wcnt[wv * 1024 + d] = (unsigned)__popcll(m);
    __syncthreads();
    unsigned prior = runb[d];
    for (int w = 0; w < 3; ++w) if (w < wv) prior += wcnt[w * 1024 + d];
    const unsigned pos = prior + lrank;
    if (last) o_all[slotbase + pos] = v;
    else { kdst[slotbase + pos] = k; idst[slotbase + pos] = v; }
    __syncthreads();
    #pragma unroll
    for (int i = 0; i < 4; ++i) {
      const int dd = i * 256 + tid;
      runb[dd] += wcnt[dd] + wcnt[1024 + dd] + wcnt[2048 + dd] + wcnt[3072 + dd];
    }
    __syncthreads();
  }
}

// ---------------------------------------------------------------------------
// Phase A: gather+embed -> LN -> in_proj (MFMA) -> conv+silu -> x_proj (MFMA)
// LDS arena (50016 B): xcb16[35][264] u16 | hfp[35][132] f32 (xc16 overlays) |
//                      hb16[48][136] u16
// ---------------------------------------------------------------------------
constexpr int HF_ = 132;    // hfp fp32 stride
constexpr int HB_ = 136;    // hb16 ushort stride
constexpr int XB_ = 264;    // xcb16 / xc16 ushort stride
constexpr int OFF_HFP = 18480;
constexpr int OFF_HB16 = 36960;
constexpr int SMEM_A = 50016;

__global__ __launch_bounds__(256) void k_phaseA(
    const float* __restrict__ feats1, const float* __restrict__ feats2,
    const float* __restrict__ pos1, const float* __restrict__ pos2,
    const float* __restrict__ pe_w, const float* __restrict__ pe_b,
    MP p1, MP p2, const int* __restrict__ o_all,
    const unsigned short* __restrict__ w16,
    __hip_bfloat16* __restrict__ xc_g, __hip_bfloat16* __restrict__ z_g,
    float* __restrict__ dbl_g)
{
  const int blk = blockIdx.x;
  bool is1; int b, tile;
  if (blk < 4 * NTILE1_) { is1 = true; b = blk / NTILE1_; tile = blk % NTILE1_; }
  else { const int r = blk - 4 * NTILE1_; is1 = false; b = r / NTILE2_; tile = r % NTILE2_; }
  const int L = is1 ? L1_ : L2_;
  const int slotbase = is1 ? b * L1_ : N1_ + b * L2_;
  const float* feats = is1 ? feats1 + (size_t)b * L1_ * DM_ : feats2 + (size_t)b * L2_ * DM_;
  const float* pos = is1 ? pos1 + (size_t)b * L1_ * 3 : pos2 + (size_t)b * L2_ * 3;
  const MP P = is1 ? p2 : p1;       // s1 uses m2 params, s2 uses m1
  const unsigned short* iw16 = w16 + (is1 ? IN2_OFF : IN1_OFF);
  const unsigned short* xp16 = w16 + (is1 ? XP2_OFF : XP1_OFF);
  const bool rev = is1;             // s1 runs reversed
  const int t0 = tile * TA_;
  const int pstart = rev ? t0 : t0 - 3;
  const int lsh = rev ? 0 : 3;

  __shared__ char smem[SMEM_A];
  unsigned short* xcb16 = (unsigned short*)smem;              // [35][264]
  float* hfp = (float*)(smem + OFF_HFP);                      // [35][132]
  unsigned short* xc16 = (unsigned short*)(smem + OFF_HFP);   // [32][264] (later)
  unsigned short* hb16 = (unsigned short*)(smem + OFF_HB16);  // [48][136]

  const int tid = threadIdx.x;
  const int lane = tid & 63, wv = tid >> 6;
  const int l15 = lane & 15, quad = lane >> 4;

  // P0: zero hb16 + gather + positional embed into hfp
  {
    unsigned* hz = (unsigned*)hb16;
    for (int i = tid; i < 48 * HB_ / 2; i += 256) hz[i] = 0;
    const int c = tid & 127;
    const int half = tid >> 7;
    const float pw0 = pe_w[c * 3 + 0], pw1 = pe_w[c * 3 + 1], pw2 = pe_w[c * 3 + 2];
    const float pb = pe_b[c];
    for (int lt = half; lt < TAH_; lt += 2) {
      const int p = pstart + lt;
      if (p >= 0 && p < L) {
        const int orig = o_all[slotbase + p];
        const float* fr = feats + (size_t)orig * DM_;
        const float* pr = pos + (size_t)orig * 3;
        hfp[lt * HF_ + c] = fr[c] + pr[0] * pw0 + pr[1] * pw1 + pr[2] * pw2 + pb;
      }
    }
  }
  __syncthreads();
  // P1: LayerNorm -> hb16 (bf16); invalid rows stay zero
  {
    for (int lt = wv; lt < TAH_; lt += 4) {
      const int p = pstart + lt;
      if (p < 0 || p >= L) continue;
      float x0 = hfp[lt * HF_ + lane], x1 = hfp[lt * HF_ + lane + 64];
      float s = x0 + x1, q = x0 * x0 + x1 * x1;
      #pragma unroll
      for (int off = 32; off; off >>= 1) {
        s += __shfl_xor(s, off, 64);
        q += __shfl_xor(q, off, 64);
      }
      const float mu = s * (1.f / 128.f);
      const float rs = rsqrtf(q * (1.f / 128.f) - mu * mu + 1e-5f);
      hb16[lt * HB_ + lane]      = f2bf((x0 - mu) * rs * P.ln_g[lane]      + P.ln_b[lane]);
      hb16[lt * HB_ + lane + 64] = f2bf((x1 - mu) * rs * P.ln_g[lane + 64] + P.ln_b[lane + 64]);
    }
  }
  __syncthreads();
  // P2: in_proj via MFMA. C[48x512] = hb16[48x128] @ in_w^T. Wave w: n-tiles nn*4+w.
  {
    short8 afr[3][4];
    #pragma unroll
    for (int mt = 0; mt < 3; ++mt)
      #pragma unroll
      for (int t = 0; t < 4; ++t)
        afr[mt][t] = *(const short8*)(hb16 + (mt * 16 + l15) * HB_ + t * 32 + quad * 8);
    for (int nn = 0; nn < 8; ++nn) {
      const int ntile = nn * 4 + wv;
      f32x4 acc[3];
      #pragma unroll
      for (int mt = 0; mt < 3; ++mt) acc[mt] = (f32x4){0.f, 0.f, 0.f, 0.f};
      #pragma unroll
      for (int t = 0; t < 4; ++t) {
        const short8 bfr = *(const short8*)(iw16 + (size_t)(ntile * 16 + l15) * DM_ + t * 32 + quad * 8);
        #pragma unroll
        for (int mt = 0; mt < 3; ++mt)
          acc[mt] = __builtin_amdgcn_mfma_f32_16x16x32_bf16(afr[mt][t], bfr, acc[mt], 0, 0, 0);
      }
      const int col = ntile * 16 + l15;
      if (col < 256) {
        #pragma unroll
        for (int mt = 0; mt < 3; ++mt)
          #pragma unroll
          for (int r = 0; r < 4; ++r) {
            const int row = mt * 16 + quad * 4 + r;
            if (row < TAH_) xcb16[row * XB_ + col] = f2bf(acc[mt][r]);
          }
      } else {
        #pragma unroll
        for (int mt = 0; mt < 3; ++mt)
          #pragma unroll
          for (int r = 0; r < 4; ++r) {
            const int row = mt * 16 + quad * 4 + r;
            const int m = row - lsh;
            if (m >= 0 && m < TA_)
              z_g[(size_t)(slotbase + t0 + m) * DI_ + (col - 256)] = __float2bfloat16(acc[mt][r]);
          }
      }
    }
  }
  __syncthreads();
  // P3: depthwise causal conv (dir-flipped for rev) + bias + silu -> xc_g + xc16
  {
    const int d = tid;
    const float w0 = P.conv_w[d * 4 + 0], w1 = P.conv_w[d * 4 + 1],
                w2 = P.conv_w[d * 4 + 2], w3 = P.conv_w[d * 4 + 3];
    const float cb = P.conv_b[d];
    float x0 = bf2f(xcb16[0 * XB_ + d]), x1 = bf2f(xcb16[1 * XB_ + d]),
          x2 = bf2f(xcb16[2 * XB_ + d]);
    unsigned short out16[TA_];
    #pragma unroll
    for (int m = 0; m < TA_; ++m) {
      const float x3 = bf2f(xcb16[(m + 3) * XB_ + d]);
      float v;
      if (rev) v = w3 * x0 + w2 * x1 + w1 * x2 + w0 * x3;
      else     v = w0 * x0 + w1 * x1 + w2 * x2 + w3 * x3;
      v += cb;
      v = v * (1.f / (1.f + __expf(-v)));
      const unsigned short vb = f2bf(v);
      out16[m] = vb;
      xc_g[(size_t)(slotbase + t0 + m) * DI_ + d] = __builtin_bit_cast(__hip_bfloat16, vb);
      x0 = x1; x1 = x2; x2 = x3;
    }
    __syncthreads();   // xc16 overlays hfp; all reads of xcb16 done per-thread-column
    #pragma unroll
    for (int m = 0; m < TA_; ++m) xc16[m * XB_ + d] = out16[m];
  }
  __syncthreads();
  // P4: x_proj via MFMA. dbl[32x40] = xc16[32x256] @ xproj_w^T. Waves 0-2.
  if (wv < 3) {
    f32x4 acc0 = (f32x4){0.f,0.f,0.f,0.f}, acc1 = acc0;
    #pragma unroll
    for (int t = 0; t < 8; ++t) {
      const short8 bfr = *(const short8*)(xp16 + (size_t)(wv * 16 + l15) * DI_ + t * 32 + quad * 8);
      const short8 a0 = *(const short8*)(xc16 + (l15) * XB_ + t * 32 + quad * 8);
      const short8 a1 = *(const short8*)(xc16 + (16 + l15) * XB_ + t * 32 + quad * 8);
      acc0 = __builtin_amdgcn_mfma_f32_16x16x32_bf16(a0, bfr, acc0, 0, 0, 0);
      acc1 = __builtin_amdgcn_mfma_f32_16x16x32_bf16(a1, bfr, acc1, 0, 0, 0);
    }
    const int col = wv * 16 + l15;
    if (col < 40) {
      #pragma unroll
      for (int r = 0; r < 4; ++r) {
        dbl_g[(size_t)(slotbase + t0 + quad * 4 + r) * 40 + col] = acc0[r];
        dbl_g[(size_t)(slotbase + t0 + 16 + quad * 4 + r) * 40 + col] = acc1[r];
      }
    }
  }
}

// ---------------------------------------------------------------------------
// Scan pass 1: per-chunk local state (h0=0) + sum(dt). 1 block per chunk, d=tid.
// ---------------------------------------------------------------------------
__global__ __launch_bounds__(256) void k_scan1(
    MP p1, MP p2,
    const __hip_bfloat16* __restrict__ xc_g, const float* __restrict__ dbl_g,
    float* __restrict__ hloc, float* __restrict__ sumdt_g)
{
  const int blk = blockIdx.x;
  bool is1; int b, pc;
  if (blk < 4 * NCH1_) { is1 = true; b = blk / NCH1_; pc = blk % NCH1_; }
  else { const int r = blk - 4 * NCH1_; is1 = false; b = r / NCH2_; pc = r % NCH2_; }
  const MP P = is1 ? p2 : p1;
  const int L = is1 ? L1_ : L2_;
  const bool rev = is1;
  const int slotbase = is1 ? b * L1_ : N1_ + b * L2_;
  const int d = threadIdx.x;
  float A[DS_];
  #pragma unroll
  for (int s = 0; s < DS_; ++s) A[s] = -__expf(P.A_log[d * DS_ + s]);
  float dtw[DTR_];
  #pragma unroll
  for (int r = 0; r < DTR_; ++r) dtw[r] = P.dtproj_w[d * DTR_ + r];
  const float dtb = P.dtproj_b[d];
  float h[DS_];
  #pragma unroll
  for (int s = 0; s < DS_; ++s) h[s] = 0.f;
  float sdt = 0.f;
  const int s0 = rev ? (L - (pc + 1) * TS_) : pc * TS_;
  for (int i = 0; i < TS_; ++i) {
    const int p = rev ? (s0 + TS_ - 1 - i) : (s0 + i);
    const size_t slot = (size_t)(slotbase + p);
    const float* dr = dbl_g + slot * 40;
    const float4 q0 = *(const float4*)(dr);
    const float4 q1 = *(const float4*)(dr + 4);
    const float dtraw = dtb + q0.x*dtw[0] + q0.y*dtw[1] + q0.z*dtw[2] + q0.w*dtw[3]
                            + q1.x*dtw[4] + q1.y*dtw[5] + q1.z*dtw[6] + q1.w*dtw[7];
    const float dt = softplusf(dtraw);
    const float u = __bfloat162float(xc_g[slot * DI_ + d]);
    const float du = dt * u;
    sdt += dt;
    float Bv[16];
    *(float4*)&Bv[0]  = *(const float4*)(dr + 8);
    *(float4*)&Bv[4]  = *(const float4*)(dr + 12);
    *(float4*)&Bv[8]  = *(const float4*)(dr + 16);
    *(float4*)&Bv[12] = *(const float4*)(dr + 20);
    #pragma unroll
    for (int s = 0; s < DS_; ++s) {
      const float a = __expf(dt * A[s]);
      h[s] = a * h[s] + du * Bv[s];
    }
  }
  float* hl = hloc + (size_t)blk * DS_ * DI_;
  #pragma unroll
  for (int s = 0; s < DS_; ++s) hl[s * DI_ + d] = h[s];
  sumdt_g[(size_t)blk * DI_ + d] = sdt;
}

// ---------------------------------------------------------------------------
// Scan pass 2: chain chunks. h_out = exp(A*sumdt)*h_in + h_local. 128 blocks.
// ---------------------------------------------------------------------------
__global__ __launch_bounds__(256) void k_scan2(
    MP p1, MP p2, const float* __restrict__ hloc,
    const float* __restrict__ sumdt_g, float* __restrict__ hin)
{
  const int seq = blockIdx.x >> 4;
  const int s = blockIdx.x & 15;
  const bool is1 = seq < 4;
  const int b = is1 ? seq : seq - 4;
  const MP P = is1 ? p2 : p1;
  const int nch = is1 ? NCH1_ : NCH2_;
  const int chbase = is1 ? b * NCH1_ : 4 * NCH1_ + b * NCH2_;
  const int d = threadIdx.x;
  const float A = -__expf(P.A_log[d * DS_ + s]);
  float carry = 0.f;
  for (int pc = 0; pc < nch; ++pc) {
    const size_t idx = (size_t)(chbase + pc);
    const float sdt = sumdt_g[idx * DI_ + d];
    hin[idx * DS_ * DI_ + s * DI_ + d] = carry;
    carry = __expf(A * sdt) * carry + hloc[idx * DS_ * DI_ + s * DI_ + d];
  }
}

// ---------------------------------------------------------------------------
// Scan pass 3: replay chunk from h_in, emit y (bf16).
// ---------------------------------------------------------------------------
__global__ __launch_bounds__(256) void k_scan3(
    MP p1, MP p2,
    const __hip_bfloat16* __restrict__ xc_g, const float* __restrict__ dbl_g,
    const float* __restrict__ hin, __hip_bfloat16* __restrict__ y_g)
{
  const int blk = blockIdx.x;
  bool is1; int b, pc;
  if (blk < 4 * NCH1_) { is1 = true; b = blk / NCH1_; pc = blk % NCH1_; }
  else { const int r = blk - 4 * NCH1_; is1 = false; b = r / NCH2_; pc = r % NCH2_; }
  const MP P = is1 ? p2 : p1;
  const int L = is1 ? L1_ : L2_;
  const bool rev = is1;
  const int slotbase = is1 ? b * L1_ : N1_ + b * L2_;
  const int d = threadIdx.x;
  float A[DS_];
  #pragma unroll
  for (int s = 0; s < DS_; ++s) A[s] = -__expf(P.A_log[d * DS_ + s]);
  float dtw[DTR_];
  #pragma unroll
  for (int r = 0; r < DTR_; ++r) dtw[r] = P.dtproj_w[d * DTR_ + r];
  const float dtb = P.dtproj_b[d];
  float h[DS_];
  const float* hi = hin + (size_t)blk * DS_ * DI_;
  #pragma unroll
  for (int s = 0; s < DS_; ++s) h[s] = hi[s * DI_ + d];
  const int s0 = rev ? (L - (pc + 1) * TS_) : pc * TS_;
  for (int i = 0; i < TS_; ++i) {
    const int p = rev ? (s0 + TS_ - 1 - i) : (s0 + i);
    const size_t slot = (size_t)(slotbase + p);
    const float* dr = dbl_g + slot * 40;
    const float4 q0 = *(const float4*)(dr);
    const float4 q1 = *(const float4*)(dr + 4);
    const float dtraw = dtb + q0.x*dtw[0] + q0.y*dtw[1] + q0.z*dtw[2] + q0.w*dtw[3]
                            + q1.x*dtw[4] + q1.y*dtw[5] + q1.z*dtw[6] + q1.w*dtw[7];
    const float dt = softplusf(dtraw);
    const float u = __bfloat162float(xc_g[slot * DI_ + d]);
    const float du = dt * u;
    float Bv[16], Cv[16];
    *(float4*)&Bv[0]  = *(const float4*)(dr + 8);
    *(float4*)&Bv[4]  = *(const float4*)(dr + 12);
    *(float4*)&Bv[8]  = *(const float4*)(dr + 16);
    *(float4*)&Bv[12] = *(const float4*)(dr + 20);
    *(float4*)&Cv[0]  = *(const float4*)(dr + 24);
    *(float4*)&Cv[4]  = *(const float4*)(dr + 28);
    *(float4*)&Cv[8]  = *(const float4*)(dr + 32);
    *(float4*)&Cv[12] = *(const float4*)(dr + 36);
    float y = 0.f;
    #pragma unroll
    for (int s = 0; s < DS_; ++s) {
      const float a = __expf(dt * A[s]);
      h[s] = a * h[s] + du * Bv[s];
      y += h[s] * Cv[s];
    }
    y_g[slot * DI_ + d] = __float2bfloat16(y);
  }
}

// ---------------------------------------------------------------------------
// Final: v = (y + xc*D)*silu(z); out_proj (MFMA); output LN; scatter via perm.
// ---------------------------------------------------------------------------
constexpr int OB_ = 132;
__global__ __launch_bounds__(256) void k_final(
    MP p1, MP p2,
    const __hip_bfloat16* __restrict__ y_g, const __hip_bfloat16* __restrict__ xc_g,
    const __hip_bfloat16* __restrict__ z_g, const int* __restrict__ o_all,
    const unsigned short* __restrict__ w16,
    const float* __restrict__ norm_g, const float* __restrict__ norm_b,
    const float* __restrict__ normb_g, const float* __restrict__ normb_b,
    float* __restrict__ out)
{
  const int blk = blockIdx.x;
  bool is1; int b, tile;
  if (blk < 4 * NTILE1_) { is1 = true; b = blk / NTILE1_; tile = blk % NTILE1_; }
  else { const int r = blk - 4 * NTILE1_; is1 = false; b = r / NTILE2_; tile = r % NTILE2_; }
  const MP P = is1 ? p2 : p1;
  const unsigned short* W = w16 + (is1 ? OW2_OFF : OW1_OFF);
  const float* gg = is1 ? normb_g : norm_g;
  const float* gb = is1 ? normb_b : norm_b;
  const int slotbase = is1 ? b * L1_ : N1_ + b * L2_;
  const int t0 = tile * TA_;
  __shared__ unsigned short v16[TA_ * XB_];  // 16896 B
  __shared__ float obuf[TA_ * OB_];          // 16896 B
  const int tid = threadIdx.x;
  const int lane = tid & 63, wv = tid >> 6;
  const int l15 = lane & 15, quad = lane >> 4;
  {
    const int d = tid;
    const float Dp = P.Dp[d];
    for (int m = 0; m < TA_; ++m) {
      const size_t slot = (size_t)(slotbase + t0 + m);
      const float y = __bfloat162float(y_g[slot * DI_ + d]);
      const float xcv = __bfloat162float(xc_g[slot * DI_ + d]);
      const float zv = __bfloat162float(z_g[slot * DI_ + d]);
      v16[m * XB_ + d] = f2bf((y + xcv * Dp) * (zv / (1.f + __expf(-zv))));
    }
  }
  __syncthreads();
  // out_proj MFMA: [32x128] = v16[32x256] @ out_w^T. Wave w: n-tiles w, w+4.
  for (int nn = 0; nn < 2; ++nn) {
    const int ntile = wv + nn * 4;
    f32x4 acc0 = (f32x4){0.f,0.f,0.f,0.f}, acc1 = acc0;
    #pragma unroll
    for (int t = 0; t < 8; ++t) {
      const short8 bfr = *(const short8*)(W + (size_t)(ntile * 16 + l15) * DI_ + t * 32 + quad * 8);
      const short8 a0 = *(const short8*)(v16 + (l15) * XB_ + t * 32 + quad * 8);
      const short8 a1 = *(const short8*)(v16 + (16 + l15) * XB_ + t * 32 + quad * 8);
      acc0 = __builtin_amdgcn_mfma_f32_16x16x32_bf16(a0, bfr, acc0, 0, 0, 0);
      acc1 = __builtin_amdgcn_mfma_f32_16x16x32_bf16(a1, bfr, acc1, 0, 0, 0);
    }
    const int col = ntile * 16 + l15;
    #pragma unroll
    for (int r = 0; r < 4; ++r) {
      obuf[(quad * 4 + r) * OB_ + col] = acc0[r];
      obuf[(16 + quad * 4 + r) * OB_ + col] = acc1[r];
    }
  }
  __syncthreads();
  {
    for (int m = wv; m < TA_; m += 4) {
      float x0 = obuf[m * OB_ + lane], x1 = obuf[m * OB_ + lane + 64];
      float s = x0 + x1, q = x0 * x0 + x1 * x1;
      #pragma unroll
      for (int off = 32; off; off >>= 1) {
        s += __shfl_xor(s, off, 64);
        q += __shfl_xor(q, off, 64);
      }
      const float mu = s * (1.f / 128.f);
      const float rs = rsqrtf(q * (1.f / 128.f) - mu * mu + 1e-5f);
      const int orig = o_all[slotbase + t0 + m];
      float* orow = out + (size_t)(slotbase + orig) * DM_;
      orow[lane]      = (x0 - mu) * rs * gg[lane]      + gb[lane];
      orow[lane + 64] = (x1 - mu) * rs * gg[lane + 64] + gb[lane + 64];
    }
  }
}

// ---------------------------------------------------------------------------
extern "C" void kernel_launch(void* const* d_in, const int* in_sizes, int n_in,
                              void* d_out, int out_size, void* d_ws, size_t ws_size,
                              hipStream_t stream)
{
  (void)in_sizes; (void)n_in; (void)out_size; (void)ws_size;
  const float* feats1 = (const float*)d_in[0];
  const float* feats2 = (const float*)d_in[1];
  const float* pos1   = (const float*)d_in[2];
  const float* pos2   = (const float*)d_in[3];
  const int*   hil1   = (const int*)d_in[4];
  const int*   hil2   = (const int*)d_in[5];
  const float* pe_w   = (const float*)d_in[6];
  const float* pe_b   = (const float*)d_in[7];
  const float* norm_g  = (const float*)d_in[8];
  const float* norm_b  = (const float*)d_in[9];
  const float* normb_g = (const float*)d_in[10];
  const float* normb_b = (const float*)d_in[11];
  MP p1 { (const float*)d_in[12], (const float*)d_in[13], (const float*)d_in[14],
          (const float*)d_in[15], (const float*)d_in[16], (const float*)d_in[17],
          (const float*)d_in[18], (const float*)d_in[19], (const float*)d_in[20],
          (const float*)d_in[21], (const float*)d_in[22] };
  MP p2 { (const float*)d_in[23], (const float*)d_in[24], (const float*)d_in[25],
          (const float*)d_in[26], (const float*)d_in[27], (const float*)d_in[28],
          (const float*)d_in[29], (const float*)d_in[30], (const float*)d_in[31],
          (const float*)d_in[32], (const float*)d_in[33] };

  char* w = (char*)d_ws;
  auto take = [&](size_t bytes) -> char* {
    char* p = w; w += (bytes + 255) & ~(size_t)255; return p;
  };
  int* o_all = (int*)take((size_t)TOT_ * 4);
  unsigned* kA = (unsigned*)take((size_t)TOT_ * 4);
  int* iA = (int*)take((size_t)TOT_ * 4);
  unsigned* kB = (unsigned*)take((size_t)TOT_ * 4);
  int* iB = (int*)take((size_t)TOT_ * 4);
  unsigned* histg = (unsigned*)take((size_t)NST_ * 1024 * 4);
  unsigned* offg  = (unsigned*)take((size_t)NST_ * 1024 * 4);
  __hip_bfloat16* xc = (__hip_bfloat16*)take((size_t)TOT_ * DI_ * 2);
  __hip_bfloat16* zb = (__hip_bfloat16*)take((size_t)TOT_ * DI_ * 2);
  __hip_bfloat16* yb = (__hip_bfloat16*)take((size_t)TOT_ * DI_ * 2);
  float* dbl = (float*)take((size_t)TOT_ * 40 * 4);
  float* hloc = (float*)take((size_t)NCHUNKS_ * DS_ * DI_ * 4);
  float* hin  = (float*)take((size_t)NCHUNKS_ * DS_ * DI_ * 4);
  float* sdt  = (float*)take((size_t)NCHUNKS_ * DI_ * 4);
  unsigned short* w16 = (unsigned short*)take((size_t)W16_TOT * 2);

  hipLaunchKernelGGL(k_prep, dim3((W16_TOT + 255) / 256), dim3(256), 0, stream,
                     p1.in_w, p1.xproj_w, p1.out_w, p2.in_w, p2.xproj_w, p2.out_w, w16);
  // radix sort: 3 passes of (hist, scan, scatter)
  hipLaunchKernelGGL(k_hist, dim3(NST_), dim3(256), 0, stream,
                     hil1, hil2, kB, histg, 0, 1);
  hipLaunchKernelGGL(k_scanoff, dim3(8), dim3(256), 0, stream, histg, offg);
  hipLaunchKernelGGL(k_scatter, dim3(NST_), dim3(256), 0, stream,
                     hil1, hil2, kB, iB, offg, kB, iB, o_all, 0, 1, 0);
  hipLaunchKernelGGL(k_hist, dim3(NST_), dim3(256), 0, stream,
                     hil1, hil2, kB, histg, 10, 0);
  hipLaunchKernelGGL(k_scanoff, dim3(8), dim3(256), 0, stream, histg, offg);
  hipLaunchKernelGGL(k_scatter, dim3(NST_), dim3(256), 0, stream,
                     hil1, hil2, kB, iB, offg, kA, iA, o_all, 10, 0, 0);
  hipLaunchKernelGGL(k_hist, dim3(NST_), dim3(256), 0, stream,
                     hil1, hil2, kA, histg, 20, 0);
  hipLaunchKernelGGL(k_scanoff, dim3(8), dim3(256), 0, stream, histg, offg);
  hipLaunchKernelGGL(k_scatter, dim3(NST_), dim3(256), 0, stream,
                     hil1, hil2, kA, iA, offg, kB, iB, o_all, 20, 0, 1);

  hipLaunchKernelGGL(k_phaseA, dim3(NTILES_), dim3(256), 0, stream,
                     feats1, feats2, pos1, pos2, pe_w, pe_b, p1, p2, o_all, w16,
                     xc, zb, dbl);
  hipLaunchKernelGGL(k_scan1, dim3(NCHUNKS_), dim3(256), 0, stream,
                     p1, p2, xc, dbl, hloc, sdt);
  hipLaunchKernelGGL(k_scan2, dim3(128), dim3(256), 0, stream,
                     p1, p2, hloc, sdt, hin);
  hipLaunchKernelGGL(k_scan3, dim3(NCHUNKS_), dim3(256), 0, stream,
                     p1, p2, xc, dbl, hin, yb);
  hipLaunchKernelGGL(k_final, dim3(NTILES_), dim3(256), 0, stream,
                     p1, p2, yb, xc, zb, o_all, w16, norm_g, norm_b, normb_g, normb_b,
                     (float*)d_out);
}

// Round 4
// 953.354 us; speedup vs baseline: 3.8408x; 1.3934x over previous
//
#include <hip/hip_runtime.h>
#include <hip/hip_bf16.h>

#define DEV __device__ __forceinline__

constexpr int BATCH_ = 4;
constexpr int N1_ = 131072;
constexpr int N2_ = 32768;
constexpr int L1_ = N1_ / BATCH_;   // 32768
constexpr int L2_ = N2_ / BATCH_;   // 8192
constexpr int DM_ = 128;
constexpr int DI_ = 256;
constexpr int DS_ = 16;
constexpr int DTR_ = 8;
constexpr int TOT_ = N1_ + N2_;     // 163840

constexpr int TA_ = 32;             // phase A / final tile (tokens)
constexpr int TAH_ = TA_ + 3;       // + conv halo
constexpr int NTILE1_ = L1_ / TA_;  // 1024
constexpr int NTILE2_ = L2_ / TA_;  // 256
constexpr int NTILES_ = 4 * NTILE1_ + 4 * NTILE2_;  // 5120

constexpr int TS_ = 128;            // scan chunk length
constexpr int NCH1_ = L1_ / TS_;    // 256
constexpr int NCH2_ = L2_ / TS_;    // 64
constexpr int NCHUNKS_ = 4 * NCH1_ + 4 * NCH2_;     // 1280

// radix sort: 10-bit digits, 3 passes, 1024-elem tiles
constexpr int NST_ = 160;           // 4*32 + 4*8 sort tiles

// bf16 weight arena offsets (elements)
constexpr int IN1_OFF = 0;          // in_w model1 [512][128]
constexpr int IN2_OFF = 65536;
constexpr int XP1_OFF = 131072;     // xproj padded [48][256]
constexpr int XP2_OFF = 143360;
constexpr int OW1_OFF = 155648;     // out_w [128][256]
constexpr int OW2_OFF = 188416;
constexpr int W16_TOT = 221184;

typedef short short8 __attribute__((ext_vector_type(8)));
typedef float f32x4 __attribute__((ext_vector_type(4)));

struct MP {
  const float* ln_g; const float* ln_b; const float* in_w;
  const float* conv_w; const float* conv_b; const float* xproj_w;
  const float* dtproj_w; const float* dtproj_b; const float* A_log;
  const float* Dp; const float* out_w;
};

DEV float softplusf(float x) {
  // max(x,0) + log(1 + exp(-|x|)) using fast-log (no libm log1pf slow path)
  return fmaxf(x, 0.f) + __logf(1.f + __expf(-fabsf(x)));
}

DEV unsigned short f2bf(float f) {
  unsigned u = __builtin_bit_cast(unsigned, f);
  u += 0x7fffu + ((u >> 16) & 1u);
  return (unsigned short)(u >> 16);
}
DEV float bf2f(unsigned short s) {
  unsigned u = ((unsigned)s) << 16;
  return __builtin_bit_cast(float, u);
}

DEV void sort_tile_info(int tile, int& seg, int& tis, int& slotbase) {
  if (tile < 128) { seg = tile >> 5; tis = tile & 31; slotbase = seg * L1_; }
  else { seg = 4 + ((tile - 128) >> 3); tis = (tile - 128) & 7; slotbase = N1_ + (seg - 4) * L2_; }
}

// ---------------------------------------------------------------------------
// Weight prep: fp32 -> bf16 copies (xproj padded 40->48 rows with zeros).
// ---------------------------------------------------------------------------
__global__ __launch_bounds__(256) void k_prep(
    const float* __restrict__ in_w1, const float* __restrict__ xp1,
    const float* __restrict__ ow1,
    const float* __restrict__ in_w2, const float* __restrict__ xp2,
    const float* __restrict__ ow2,
    unsigned short* __restrict__ w16)
{
  const int i = blockIdx.x * 256 + threadIdx.x;
  if (i >= W16_TOT) return;
  float v;
  if (i < IN2_OFF) v = in_w1[i - IN1_OFF];
  else if (i < XP1_OFF) v = in_w2[i - IN2_OFF];
  else if (i < XP2_OFF) {
    const int j = i - XP1_OFF; const int r = j >> 8;
    v = (r < 40) ? xp1[j] : 0.f;
  } else if (i < OW1_OFF) {
    const int j = i - XP2_OFF; const int r = j >> 8;
    v = (r < 40) ? xp2[j] : 0.f;
  } else if (i < OW2_OFF) v = ow1[i - OW1_OFF];
  else v = ow2[i - OW2_OFF];
  w16[i] = f2bf(v);
}

// ---------------------------------------------------------------------------
// Radix sort pass kernels (stable, 10-bit digits).
// ---------------------------------------------------------------------------
__global__ __launch_bounds__(256) void k_hist(
    const int* __restrict__ hil1, const int* __restrict__ hil2,
    const unsigned* __restrict__ ksrc, unsigned* __restrict__ histg,
    int shift, int pass0)
{
  const int tile = blockIdx.x;
  int seg, tis, slotbase;
  sort_tile_info(tile, seg, tis, slotbase);
  const int tid = threadIdx.x;
  __shared__ unsigned h[1024];
  #pragma unroll
  for (int i = 0; i < 4; ++i) h[i * 256 + tid] = 0;
  __syncthreads();
  #pragma unroll
  for (int it = 0; it < 4; ++it) {
    const int li = tis * 1024 + it * 256 + tid;
    unsigned k;
    if (pass0) k = (unsigned)(seg < 4 ? hil1[seg * L1_ + li] : hil2[(seg - 4) * L2_ + li]);
    else       k = ksrc[slotbase + li];
    atomicAdd(&h[(k >> shift) & 1023u], 1u);
  }
  __syncthreads();
  #pragma unroll
  for (int i = 0; i < 4; ++i)
    histg[tile * 1024 + i * 256 + tid] = h[i * 256 + tid];
}

__global__ __launch_bounds__(256) void k_scanoff(
    const unsigned* __restrict__ histg, unsigned* __restrict__ offg)
{
  const int seg = blockIdx.x;
  const int ntiles = seg < 4 ? 32 : 8;
  const int tilebase = seg < 4 ? seg * 32 : 128 + (seg - 4) * 8;
  const int tid = threadIdx.x;
  const int d0 = tid * 4;
  unsigned tot[4] = {0, 0, 0, 0};
  for (int t = 0; t < ntiles; ++t) {
    const unsigned* hp = &histg[(size_t)(tilebase + t) * 1024 + d0];
    tot[0] += hp[0]; tot[1] += hp[1]; tot[2] += hp[2]; tot[3] += hp[3];
  }
  unsigned lp[4]; unsigned s = 0;
  #pragma unroll
  for (int j = 0; j < 4; ++j) { lp[j] = s; s += tot[j]; }
  const int lane = tid & 63, wv = tid >> 6;
  unsigned inc = s;
  #pragma unroll
  for (int off = 1; off < 64; off <<= 1) {
    unsigned v = (unsigned)__shfl_up((int)inc, off, 64);
    if (lane >= off) inc += v;
  }
  __shared__ unsigned wsum[4];
  if (lane == 63) wsum[wv] = inc;
  __syncthreads();
  unsigned wbase = 0;
  for (int w = 0; w < 4; ++w) if (w < wv) wbase += wsum[w];
  const unsigned base = wbase + inc - s;   // exclusive over threads
  #pragma unroll
  for (int j = 0; j < 4; ++j) {
    unsigned run = base + lp[j];
    for (int t = 0; t < ntiles; ++t) {
      offg[(size_t)(tilebase + t) * 1024 + d0 + j] = run;
      run += histg[(size_t)(tilebase + t) * 1024 + d0 + j];
    }
  }
}

__global__ __launch_bounds__(256) void k_scatter(
    const int* __restrict__ hil1, const int* __restrict__ hil2,
    const unsigned* __restrict__ ksrc, const int* __restrict__ isrc,
    const unsigned* __restrict__ offg,
    unsigned* __restrict__ kdst, int* __restrict__ idst,
    int* __restrict__ o_all, int shift, int pass0, int last)
{
  const int tile = blockIdx.x;
  int seg, tis, slotbase;
  sort_tile_info(tile, seg, tis, slotbase);
  const int tid = threadIdx.x;
  const int lane = tid & 63, wv = tid >> 6;
  __shared__ unsigned runb[1024];
  __shared__ unsigned wcnt[4 * 1024];
  #pragma unroll
  for (int i = 0; i < 4; ++i) runb[i * 256 + tid] = offg[(size_t)tile * 1024 + i * 256 + tid];
  #pragma unroll
  for (int it = 0; it < 4; ++it) {
    #pragma unroll
    for (int i = 0; i < 16; ++i) wcnt[i * 256 + tid] = 0;
    __syncthreads();
    const int li = tis * 1024 + it * 256 + tid;
    unsigned k; int v;
    if (pass0) {
      k = (unsigned)(seg < 4 ? hil1[seg * L1_ + li] : hil2[(seg - 4) * L2_ + li]);
      v = li;
    } else {
      k = ksrc[slotbase + li]; v = isrc[slotbase + li];
    }
    const unsigned d = (k >> shift) & 1023u;
    unsigned long long m = ~0ull;
    #pragma unroll
    for (int b = 0; b < 10; ++b) {
      const unsigned long long bb = __ballot((int)((d >> b) & 1u));
      m &= ((d >> b) & 1u) ? bb : ~bb;
    }
    const unsigned lrank = (unsigned)__popcll(m & ((1ull << lane) - 1ull));
    wcnt[wv * 1024 + d] = (unsigned)__popcll(m);
    __syncthreads();
    unsigned prior = runb[d];
    for (int w = 0; w < 3; ++w) if (w < wv) prior += wcnt[w * 1024 + d];
    const unsigned pos = prior + lrank;
    if (last) o_all[slotbase + pos] = v;
    else { kdst[slotbase + pos] = k; idst[slotbase + pos] = v; }
    __syncthreads();
    #pragma unroll
    for (int i = 0; i < 4; ++i) {
      const int dd = i * 256 + tid;
      runb[dd] += wcnt[dd] + wcnt[1024 + dd] + wcnt[2048 + dd] + wcnt[3072 + dd];
    }
    __syncthreads();
  }
}

// ---------------------------------------------------------------------------
// Phase A: gather+embed -> LN -> in_proj (MFMA) -> conv+silu -> x_proj (MFMA)
// ---------------------------------------------------------------------------
constexpr int HF_ = 132;    // hfp fp32 stride
constexpr int HB_ = 136;    // hb16 ushort stride
constexpr int XB_ = 264;    // xcb16 / xc16 ushort stride
constexpr int OFF_HFP = 18480;
constexpr int OFF_HB16 = 36960;
constexpr int SMEM_A = 50016;

__global__ __launch_bounds__(256) void k_phaseA(
    const float* __restrict__ feats1, const float* __restrict__ feats2,
    const float* __restrict__ pos1, const float* __restrict__ pos2,
    const float* __restrict__ pe_w, const float* __restrict__ pe_b,
    MP p1, MP p2, const int* __restrict__ o_all,
    const unsigned short* __restrict__ w16,
    __hip_bfloat16* __restrict__ xc_g, __hip_bfloat16* __restrict__ z_g,
    float* __restrict__ dbl_g)
{
  const int blk = blockIdx.x;
  bool is1; int b, tile;
  if (blk < 4 * NTILE1_) { is1 = true; b = blk / NTILE1_; tile = blk % NTILE1_; }
  else { const int r = blk - 4 * NTILE1_; is1 = false; b = r / NTILE2_; tile = r % NTILE2_; }
  const int L = is1 ? L1_ : L2_;
  const int slotbase = is1 ? b * L1_ : N1_ + b * L2_;
  const float* feats = is1 ? feats1 + (size_t)b * L1_ * DM_ : feats2 + (size_t)b * L2_ * DM_;
  const float* pos = is1 ? pos1 + (size_t)b * L1_ * 3 : pos2 + (size_t)b * L2_ * 3;
  const MP P = is1 ? p2 : p1;       // s1 uses m2 params, s2 uses m1
  const unsigned short* iw16 = w16 + (is1 ? IN2_OFF : IN1_OFF);
  const unsigned short* xp16 = w16 + (is1 ? XP2_OFF : XP1_OFF);
  const bool rev = is1;             // s1 runs reversed
  const int t0 = tile * TA_;
  const int pstart = rev ? t0 : t0 - 3;
  const int lsh = rev ? 0 : 3;

  __shared__ char smem[SMEM_A];
  unsigned short* xcb16 = (unsigned short*)smem;              // [35][264]
  float* hfp = (float*)(smem + OFF_HFP);                      // [35][132]
  unsigned short* xc16 = (unsigned short*)(smem + OFF_HFP);   // [32][264] (later)
  unsigned short* hb16 = (unsigned short*)(smem + OFF_HB16);  // [48][136]

  const int tid = threadIdx.x;
  const int lane = tid & 63, wv = tid >> 6;
  const int l15 = lane & 15, quad = lane >> 4;

  // P0: zero hb16 + gather + positional embed into hfp
  {
    unsigned* hz = (unsigned*)hb16;
    for (int i = tid; i < 48 * HB_ / 2; i += 256) hz[i] = 0;
    const int c = tid & 127;
    const int half = tid >> 7;
    const float pw0 = pe_w[c * 3 + 0], pw1 = pe_w[c * 3 + 1], pw2 = pe_w[c * 3 + 2];
    const float pb = pe_b[c];
    for (int lt = half; lt < TAH_; lt += 2) {
      const int p = pstart + lt;
      if (p >= 0 && p < L) {
        const int orig = o_all[slotbase + p];
        const float* fr = feats + (size_t)orig * DM_;
        const float* pr = pos + (size_t)orig * 3;
        hfp[lt * HF_ + c] = fr[c] + pr[0] * pw0 + pr[1] * pw1 + pr[2] * pw2 + pb;
      }
    }
  }
  __syncthreads();
  // P1: LayerNorm -> hb16 (bf16); invalid rows stay zero
  {
    for (int lt = wv; lt < TAH_; lt += 4) {
      const int p = pstart + lt;
      if (p < 0 || p >= L) continue;
      float x0 = hfp[lt * HF_ + lane], x1 = hfp[lt * HF_ + lane + 64];
      float s = x0 + x1, q = x0 * x0 + x1 * x1;
      #pragma unroll
      for (int off = 32; off; off >>= 1) {
        s += __shfl_xor(s, off, 64);
        q += __shfl_xor(q, off, 64);
      }
      const float mu = s * (1.f / 128.f);
      const float rs = rsqrtf(q * (1.f / 128.f) - mu * mu + 1e-5f);
      hb16[lt * HB_ + lane]      = f2bf((x0 - mu) * rs * P.ln_g[lane]      + P.ln_b[lane]);
      hb16[lt * HB_ + lane + 64] = f2bf((x1 - mu) * rs * P.ln_g[lane + 64] + P.ln_b[lane + 64]);
    }
  }
  __syncthreads();
  // P2: in_proj via MFMA. C[48x512] = hb16[48x128] @ in_w^T.
  {
    short8 afr[3][4];
    #pragma unroll
    for (int mt = 0; mt < 3; ++mt)
      #pragma unroll
      for (int t = 0; t < 4; ++t)
        afr[mt][t] = *(const short8*)(hb16 + (mt * 16 + l15) * HB_ + t * 32 + quad * 8);
    for (int nn = 0; nn < 8; ++nn) {
      const int ntile = nn * 4 + wv;
      f32x4 acc[3];
      #pragma unroll
      for (int mt = 0; mt < 3; ++mt) acc[mt] = (f32x4){0.f, 0.f, 0.f, 0.f};
      #pragma unroll
      for (int t = 0; t < 4; ++t) {
        const short8 bfr = *(const short8*)(iw16 + (size_t)(ntile * 16 + l15) * DM_ + t * 32 + quad * 8);
        #pragma unroll
        for (int mt = 0; mt < 3; ++mt)
          acc[mt] = __builtin_amdgcn_mfma_f32_16x16x32_bf16(afr[mt][t], bfr, acc[mt], 0, 0, 0);
      }
      const int col = ntile * 16 + l15;
      if (col < 256) {
        #pragma unroll
        for (int mt = 0; mt < 3; ++mt)
          #pragma unroll
          for (int r = 0; r < 4; ++r) {
            const int row = mt * 16 + quad * 4 + r;
            if (row < TAH_) xcb16[row * XB_ + col] = f2bf(acc[mt][r]);
          }
      } else {
        #pragma unroll
        for (int mt = 0; mt < 3; ++mt)
          #pragma unroll
          for (int r = 0; r < 4; ++r) {
            const int row = mt * 16 + quad * 4 + r;
            const int m = row - lsh;
            if (m >= 0 && m < TA_)
              z_g[(size_t)(slotbase + t0 + m) * DI_ + (col - 256)] = __float2bfloat16(acc[mt][r]);
          }
      }
    }
  }
  __syncthreads();
  // P3: depthwise causal conv (dir-flipped for rev) + bias + silu -> xc_g + xc16
  {
    const int d = tid;
    const float w0 = P.conv_w[d * 4 + 0], w1 = P.conv_w[d * 4 + 1],
                w2 = P.conv_w[d * 4 + 2], w3 = P.conv_w[d * 4 + 3];
    const float cb = P.conv_b[d];
    float x0 = bf2f(xcb16[0 * XB_ + d]), x1 = bf2f(xcb16[1 * XB_ + d]),
          x2 = bf2f(xcb16[2 * XB_ + d]);
    unsigned short out16[TA_];
    #pragma unroll
    for (int m = 0; m < TA_; ++m) {
      const float x3 = bf2f(xcb16[(m + 3) * XB_ + d]);
      float v;
      if (rev) v = w3 * x0 + w2 * x1 + w1 * x2 + w0 * x3;
      else     v = w0 * x0 + w1 * x1 + w2 * x2 + w3 * x3;
      v += cb;
      v = v * (1.f / (1.f + __expf(-v)));
      const unsigned short vb = f2bf(v);
      out16[m] = vb;
      xc_g[(size_t)(slotbase + t0 + m) * DI_ + d] = __builtin_bit_cast(__hip_bfloat16, vb);
      x0 = x1; x1 = x2; x2 = x3;
    }
    __syncthreads();   // xc16 overlays hfp; all reads of xcb16 done per-thread-column
    #pragma unroll
    for (int m = 0; m < TA_; ++m) xc16[m * XB_ + d] = out16[m];
  }
  __syncthreads();
  // P4: x_proj via MFMA. dbl[32x40] = xc16[32x256] @ xproj_w^T. Waves 0-2.
  if (wv < 3) {
    f32x4 acc0 = (f32x4){0.f,0.f,0.f,0.f}, acc1 = acc0;
    #pragma unroll
    for (int t = 0; t < 8; ++t) {
      const short8 bfr = *(const short8*)(xp16 + (size_t)(wv * 16 + l15) * DI_ + t * 32 + quad * 8);
      const short8 a0 = *(const short8*)(xc16 + (l15) * XB_ + t * 32 + quad * 8);
      const short8 a1 = *(const short8*)(xc16 + (16 + l15) * XB_ + t * 32 + quad * 8);
      acc0 = __builtin_amdgcn_mfma_f32_16x16x32_bf16(a0, bfr, acc0, 0, 0, 0);
      acc1 = __builtin_amdgcn_mfma_f32_16x16x32_bf16(a1, bfr, acc1, 0, 0, 0);
    }
    const int col = wv * 16 + l15;
    if (col < 40) {
      #pragma unroll
      for (int r = 0; r < 4; ++r) {
        dbl_g[(size_t)(slotbase + t0 + quad * 4 + r) * 40 + col] = acc0[r];
        dbl_g[(size_t)(slotbase + t0 + 16 + quad * 4 + r) * 40 + col] = acc1[r];
      }
    }
  }
}

// ---------------------------------------------------------------------------
// Scan helpers: load per-thread params, check A[s] = (s+1)*A0 structure.
// ---------------------------------------------------------------------------
struct ScanP {
  float Av[DS_]; float A0; bool fast;
  float dtw[DTR_]; float dtb;
};
DEV void load_scanp(const MP& P, int d, ScanP& sp) {
  #pragma unroll
  for (int s = 0; s < DS_; ++s) sp.Av[s] = -__expf(P.A_log[d * DS_ + s]);
  sp.A0 = sp.Av[0];
  bool f = true;
  #pragma unroll
  for (int s = 0; s < DS_; ++s)
    f = f && (fabsf(sp.Av[s] - (float)(s + 1) * sp.A0) <= 1e-3f * (float)(s + 1));
  sp.fast = f;
  #pragma unroll
  for (int r = 0; r < DTR_; ++r) sp.dtw[r] = P.dtproj_w[d * DTR_ + r];
  sp.dtb = P.dtproj_b[d];
}
DEV float dt_from(const float4& q0, const float4& q1, const ScanP& sp) {
  const float dtraw = sp.dtb
      + q0.x*sp.dtw[0] + q0.y*sp.dtw[1] + q0.z*sp.dtw[2] + q0.w*sp.dtw[3]
      + q1.x*sp.dtw[4] + q1.y*sp.dtw[5] + q1.z*sp.dtw[6] + q1.w*sp.dtw[7];
  return softplusf(dtraw);
}

// ---------------------------------------------------------------------------
// Scan pass 1: per-chunk local state (h0=0) + sum(dt). 1 block per chunk, d=tid.
// ---------------------------------------------------------------------------
__global__ __launch_bounds__(256) void k_scan1(
    MP p1, MP p2,
    const __hip_bfloat16* __restrict__ xc_g, const float* __restrict__ dbl_g,
    float* __restrict__ hloc, float* __restrict__ sumdt_g)
{
  const int blk = blockIdx.x;
  bool is1; int b, pc;
  if (blk < 4 * NCH1_) { is1 = true; b = blk / NCH1_; pc = blk % NCH1_; }
  else { const int r = blk - 4 * NCH1_; is1 = false; b = r / NCH2_; pc = r % NCH2_; }
  const MP P = is1 ? p2 : p1;
  const int L = is1 ? L1_ : L2_;
  const bool rev = is1;
  const int slotbase = is1 ? b * L1_ : N1_ + b * L2_;
  const int d = threadIdx.x;
  ScanP sp; load_scanp(P, d, sp);
  const unsigned short* xcp = (const unsigned short*)xc_g;
  float h[DS_];
  #pragma unroll
  for (int s = 0; s < DS_; ++s) h[s] = 0.f;
  float sdt = 0.f;
  const int s0 = rev ? (L - (pc + 1) * TS_) : pc * TS_;
  const int dp = rev ? -1 : 1;
  int slot = slotbase + (rev ? (s0 + TS_ - 1) : s0);
  if (sp.fast) {
    const float* dr = dbl_g + (size_t)slot * 40;
    float4 q0 = *(const float4*)dr, q1 = *(const float4*)(dr + 4);
    float4 Bv[4];
    #pragma unroll
    for (int j = 0; j < 4; ++j) Bv[j] = *(const float4*)(dr + 8 + 4 * j);
    float u = bf2f(xcp[(size_t)slot * DI_ + d]);
    for (int i = 0; i < TS_; ++i) {
      const int nslot = (i + 1 < TS_) ? slot + dp : slot;
      const float* nr = dbl_g + (size_t)nslot * 40;
      float4 nq0 = *(const float4*)nr, nq1 = *(const float4*)(nr + 4);
      float4 nB[4];
      #pragma unroll
      for (int j = 0; j < 4; ++j) nB[j] = *(const float4*)(nr + 8 + 4 * j);
      const float nu = bf2f(xcp[(size_t)nslot * DI_ + d]);
      const float dt = dt_from(q0, q1, sp);
      const float du = dt * u;
      sdt += dt;
      const float e1 = __expf(dt * sp.A0);
      const float e2 = e1 * e1, e3 = e2 * e1, e4 = e2 * e2;
      float base = 1.f;
      #pragma unroll
      for (int j = 0; j < 4; ++j) {
        const float m1 = base * e1, m2 = base * e2, m3 = base * e3, m4 = base * e4;
        h[4*j+0] = m1 * h[4*j+0] + du * Bv[j].x;
        h[4*j+1] = m2 * h[4*j+1] + du * Bv[j].y;
        h[4*j+2] = m3 * h[4*j+2] + du * Bv[j].z;
        h[4*j+3] = m4 * h[4*j+3] + du * Bv[j].w;
        base = m4;
      }
      slot = nslot; q0 = nq0; q1 = nq1; u = nu;
      #pragma unroll
      for (int j = 0; j < 4; ++j) Bv[j] = nB[j];
    }
  } else {
    for (int i = 0; i < TS_; ++i) {
      const float* dr = dbl_g + (size_t)slot * 40;
      const float4 q0 = *(const float4*)dr, q1 = *(const float4*)(dr + 4);
      const float dt = dt_from(q0, q1, sp);
      const float u = bf2f(xcp[(size_t)slot * DI_ + d]);
      const float du = dt * u;
      sdt += dt;
      float Bvv[16];
      #pragma unroll
      for (int j = 0; j < 4; ++j) *(float4*)&Bvv[4*j] = *(const float4*)(dr + 8 + 4*j);
      #pragma unroll
      for (int s = 0; s < DS_; ++s)
        h[s] = __expf(dt * sp.Av[s]) * h[s] + du * Bvv[s];
      slot += dp;
    }
  }
  float* hl = hloc + (size_t)blk * DS_ * DI_;
  #pragma unroll
  for (int s = 0; s < DS_; ++s) hl[s * DI_ + d] = h[s];
  sumdt_g[(size_t)blk * DI_ + d] = sdt;
}

// ---------------------------------------------------------------------------
// Scan pass 2: chain chunks. h_out = exp(A*sumdt)*h_in + h_local. 128 blocks.
// ---------------------------------------------------------------------------
__global__ __launch_bounds__(256) void k_scan2(
    MP p1, MP p2, const float* __restrict__ hloc,
    const float* __restrict__ sumdt_g, float* __restrict__ hin)
{
  const int seq = blockIdx.x >> 4;
  const int s = blockIdx.x & 15;
  const bool is1 = seq < 4;
  const int b = is1 ? seq : seq - 4;
  const MP P = is1 ? p2 : p1;
  const int nch = is1 ? NCH1_ : NCH2_;
  const int chbase = is1 ? b * NCH1_ : 4 * NCH1_ + b * NCH2_;
  const int d = threadIdx.x;
  const float A = -__expf(P.A_log[d * DS_ + s]);
  float carry = 0.f;
  for (int pc = 0; pc < nch; ++pc) {
    const size_t idx = (size_t)(chbase + pc);
    const float sdt = sumdt_g[idx * DI_ + d];
    hin[idx * DS_ * DI_ + s * DI_ + d] = carry;
    carry = __expf(A * sdt) * carry + hloc[idx * DS_ * DI_ + s * DI_ + d];
  }
}

// ---------------------------------------------------------------------------
// Scan pass 3: replay chunk from h_in, emit v = (y + xc*D)*silu(z) (bf16),
// written IN PLACE over the z buffer (same thread, same address).
// ---------------------------------------------------------------------------
__global__ __launch_bounds__(256) void k_scan3(
    MP p1, MP p2,
    const __hip_bfloat16* __restrict__ xc_g, const float* __restrict__ dbl_g,
    const float* __restrict__ hin, __hip_bfloat16* zv_g)
{
  const int blk = blockIdx.x;
  bool is1; int b, pc;
  if (blk < 4 * NCH1_) { is1 = true; b = blk / NCH1_; pc = blk % NCH1_; }
  else { const int r = blk - 4 * NCH1_; is1 = false; b = r / NCH2_; pc = r % NCH2_; }
  const MP P = is1 ? p2 : p1;
  const int L = is1 ? L1_ : L2_;
  const bool rev = is1;
  const int slotbase = is1 ? b * L1_ : N1_ + b * L2_;
  const int d = threadIdx.x;
  ScanP sp; load_scanp(P, d, sp);
  const float Dp = P.Dp[d];
  const unsigned short* xcp = (const unsigned short*)xc_g;
  unsigned short* zvp = (unsigned short*)zv_g;
  float h[DS_];
  const float* hi = hin + (size_t)blk * DS_ * DI_;
  #pragma unroll
  for (int s = 0; s < DS_; ++s) h[s] = hi[s * DI_ + d];
  const int s0 = rev ? (L - (pc + 1) * TS_) : pc * TS_;
  const int dp = rev ? -1 : 1;
  int slot = slotbase + (rev ? (s0 + TS_ - 1) : s0);
  if (sp.fast) {
    const float* dr = dbl_g + (size_t)slot * 40;
    float4 q0 = *(const float4*)dr, q1 = *(const float4*)(dr + 4);
    float4 Bv[4], Cv[4];
    #pragma unroll
    for (int j = 0; j < 4; ++j) {
      Bv[j] = *(const float4*)(dr + 8 + 4 * j);
      Cv[j] = *(const float4*)(dr + 24 + 4 * j);
    }
    float u = bf2f(xcp[(size_t)slot * DI_ + d]);
    float zv = bf2f(zvp[(size_t)slot * DI_ + d]);
    for (int i = 0; i < TS_; ++i) {
      const int nslot = (i + 1 < TS_) ? slot + dp : slot;
      const float* nr = dbl_g + (size_t)nslot * 40;
      float4 nq0 = *(const float4*)nr, nq1 = *(const float4*)(nr + 4);
      float4 nB[4], nC[4];
      #pragma unroll
      for (int j = 0; j < 4; ++j) {
        nB[j] = *(const float4*)(nr + 8 + 4 * j);
        nC[j] = *(const float4*)(nr + 24 + 4 * j);
      }
      const float nu = bf2f(xcp[(size_t)nslot * DI_ + d]);
      const float nz = bf2f(zvp[(size_t)nslot * DI_ + d]);
      const float dt = dt_from(q0, q1, sp);
      const float du = dt * u;
      const float e1 = __expf(dt * sp.A0);
      const float e2 = e1 * e1, e3 = e2 * e1, e4 = e2 * e2;
      float base = 1.f;
      float y = 0.f;
      #pragma unroll
      for (int j = 0; j < 4; ++j) {
        const float m1 = base * e1, m2 = base * e2, m3 = base * e3, m4 = base * e4;
        h[4*j+0] = m1 * h[4*j+0] + du * Bv[j].x;  y += h[4*j+0] * Cv[j].x;
        h[4*j+1] = m2 * h[4*j+1] + du * Bv[j].y;  y += h[4*j+1] * Cv[j].y;
        h[4*j+2] = m3 * h[4*j+2] + du * Bv[j].z;  y += h[4*j+2] * Cv[j].z;
        h[4*j+3] = m4 * h[4*j+3] + du * Bv[j].w;  y += h[4*j+3] * Cv[j].w;
        base = m4;
      }
      const float sg = zv / (1.f + __expf(-zv));
      zvp[(size_t)slot * DI_ + d] = f2bf((y + u * Dp) * sg);
      slot = nslot; q0 = nq0; q1 = nq1; u = nu; zv = nz;
      #pragma unroll
      for (int j = 0; j < 4; ++j) { Bv[j] = nB[j]; Cv[j] = nC[j]; }
    }
  } else {
    for (int i = 0; i < TS_; ++i) {
      const float* dr = dbl_g + (size_t)slot * 40;
      const float4 q0 = *(const float4*)dr, q1 = *(const float4*)(dr + 4);
      const float dt = dt_from(q0, q1, sp);
      const float u = bf2f(xcp[(size_t)slot * DI_ + d]);
      const float zv = bf2f(zvp[(size_t)slot * DI_ + d]);
      const float du = dt * u;
      float Bvv[16], Cvv[16];
      #pragma unroll
      for (int j = 0; j < 4; ++j) {
        *(float4*)&Bvv[4*j] = *(const float4*)(dr + 8 + 4*j);
        *(float4*)&Cvv[4*j] = *(const float4*)(dr + 24 + 4*j);
      }
      float y = 0.f;
      #pragma unroll
      for (int s = 0; s < DS_; ++s) {
        h[s] = __expf(dt * sp.Av[s]) * h[s] + du * Bvv[s];
        y += h[s] * Cvv[s];
      }
      const float sg = zv / (1.f + __expf(-zv));
      zvp[(size_t)slot * DI_ + d] = f2bf((y + u * Dp) * sg);
      slot += dp;
    }
  }
}

// ---------------------------------------------------------------------------
// Final: read v (bf16); out_proj (MFMA); output LN; scatter via perm.
// ---------------------------------------------------------------------------
constexpr int OB_ = 132;
__global__ __launch_bounds__(256) void k_final(
    const __hip_bfloat16* __restrict__ v_g, const int* __restrict__ o_all,
    const unsigned short* __restrict__ w16,
    const float* __restrict__ norm_g, const float* __restrict__ norm_b,
    const float* __restrict__ normb_g, const float* __restrict__ normb_b,
    float* __restrict__ out)
{
  const int blk = blockIdx.x;
  bool is1; int b, tile;
  if (blk < 4 * NTILE1_) { is1 = true; b = blk / NTILE1_; tile = blk % NTILE1_; }
  else { const int r = blk - 4 * NTILE1_; is1 = false; b = r / NTILE2_; tile = r % NTILE2_; }
  const unsigned short* W = w16 + (is1 ? OW2_OFF : OW1_OFF);
  const float* gg = is1 ? normb_g : norm_g;
  const float* gb = is1 ? normb_b : norm_b;
  const int slotbase = is1 ? b * L1_ : N1_ + b * L2_;
  const int t0 = tile * TA_;
  __shared__ unsigned short v16[TA_ * XB_];  // 16896 B
  __shared__ float obuf[TA_ * OB_];          // 16896 B
  const int tid = threadIdx.x;
  const int lane = tid & 63, wv = tid >> 6;
  const int l15 = lane & 15, quad = lane >> 4;
  {
    // copy v rows (2 cols/thread as dword)
    const int c2 = tid & 127;
    const int half = tid >> 7;
    const unsigned short* vp = (const unsigned short*)v_g;
    for (int m = half * 16; m < half * 16 + 16; ++m) {
      const unsigned* src = (const unsigned*)(vp + (size_t)(slotbase + t0 + m) * DI_);
      ((unsigned*)&v16[m * XB_])[c2] = src[c2];
    }
  }
  __syncthreads();
  // out_proj MFMA: [32x128] = v16[32x256] @ out_w^T. Wave w: n-tiles w, w+4.
  for (int nn = 0; nn < 2; ++nn) {
    const int ntile = wv + nn * 4;
    f32x4 acc0 = (f32x4){0.f,0.f,0.f,0.f}, acc1 = acc0;
    #pragma unroll
    for (int t = 0; t < 8; ++t) {
      const short8 bfr = *(const short8*)(W + (size_t)(ntile * 16 + l15) * DI_ + t * 32 + quad * 8);
      const short8 a0 = *(const short8*)(v16 + (l15) * XB_ + t * 32 + quad * 8);
      const short8 a1 = *(const short8*)(v16 + (16 + l15) * XB_ + t * 32 + quad * 8);
      acc0 = __builtin_amdgcn_mfma_f32_16x16x32_bf16(a0, bfr, acc0, 0, 0, 0);
      acc1 = __builtin_amdgcn_mfma_f32_16x16x32_bf16(a1, bfr, acc1, 0, 0, 0);
    }
    const int col = ntile * 16 + l15;
    #pragma unroll
    for (int r = 0; r < 4; ++r) {
      obuf[(quad * 4 + r) * OB_ + col] = acc0[r];
      obuf[(16 + quad * 4 + r) * OB_ + col] = acc1[r];
    }
  }
  __syncthreads();
  {
    for (int m = wv; m < TA_; m += 4) {
      float x0 = obuf[m * OB_ + lane], x1 = obuf[m * OB_ + lane + 64];
      float s = x0 + x1, q = x0 * x0 + x1 * x1;
      #pragma unroll
      for (int off = 32; off; off >>= 1) {
        s += __shfl_xor(s, off, 64);
        q += __shfl_xor(q, off, 64);
      }
      const float mu = s * (1.f / 128.f);
      const float rs = rsqrtf(q * (1.f / 128.f) - mu * mu + 1e-5f);
      const int orig = o_all[slotbase + t0 + m];
      float* orow = out + (size_t)(slotbase + orig) * DM_;
      orow[lane]      = (x0 - mu) * rs * gg[lane]      + gb[lane];
      orow[lane + 64] = (x1 - mu) * rs * gg[lane + 64] + gb[lane + 64];
    }
  }
}

// ---------------------------------------------------------------------------
extern "C" void kernel_launch(void* const* d_in, const int* in_sizes, int n_in,
                              void* d_out, int out_size, void* d_ws, size_t ws_size,
                              hipStream_t stream)
{
  (void)in_sizes; (void)n_in; (void)out_size; (void)ws_size;
  const float* feats1 = (const float*)d_in[0];
  const float* feats2 = (const float*)d_in[1];
  const float* pos1   = (const float*)d_in[2];
  const float* pos2   = (const float*)d_in[3];
  const int*   hil1   = (const int*)d_in[4];
  const int*   hil2   = (const int*)d_in[5];
  const float* pe_w   = (const float*)d_in[6];
  const float* pe_b   = (const float*)d_in[7];
  const float* norm_g  = (const float*)d_in[8];
  const float* norm_b  = (const float*)d_in[9];
  const float* normb_g = (const float*)d_in[10];
  const float* normb_b = (const float*)d_in[11];
  MP p1 { (const float*)d_in[12], (const float*)d_in[13], (const float*)d_in[14],
          (const float*)d_in[15], (const float*)d_in[16], (const float*)d_in[17],
          (const float*)d_in[18], (const float*)d_in[19], (const float*)d_in[20],
          (const float*)d_in[21], (const float*)d_in[22] };
  MP p2 { (const float*)d_in[23], (const float*)d_in[24], (const float*)d_in[25],
          (const float*)d_in[26], (const float*)d_in[27], (const float*)d_in[28],
          (const float*)d_in[29], (const float*)d_in[30], (const float*)d_in[31],
          (const float*)d_in[32], (const float*)d_in[33] };

  char* w = (char*)d_ws;
  auto take = [&](size_t bytes) -> char* {
    char* p = w; w += (bytes + 255) & ~(size_t)255; return p;
  };
  int* o_all = (int*)take((size_t)TOT_ * 4);
  unsigned* kA = (unsigned*)take((size_t)TOT_ * 4);
  int* iA = (int*)take((size_t)TOT_ * 4);
  unsigned* kB = (unsigned*)take((size_t)TOT_ * 4);
  int* iB = (int*)take((size_t)TOT_ * 4);
  unsigned* histg = (unsigned*)take((size_t)NST_ * 1024 * 4);
  unsigned* offg  = (unsigned*)take((size_t)NST_ * 1024 * 4);
  __hip_bfloat16* xc = (__hip_bfloat16*)take((size_t)TOT_ * DI_ * 2);
  __hip_bfloat16* vzb = (__hip_bfloat16*)take((size_t)TOT_ * DI_ * 2);  // z, then v
  float* dbl = (float*)take((size_t)TOT_ * 40 * 4);
  float* hloc = (float*)take((size_t)NCHUNKS_ * DS_ * DI_ * 4);
  float* hin  = (float*)take((size_t)NCHUNKS_ * DS_ * DI_ * 4);
  float* sdt  = (float*)take((size_t)NCHUNKS_ * DI_ * 4);
  unsigned short* w16 = (unsigned short*)take((size_t)W16_TOT * 2);

  hipLaunchKernelGGL(k_prep, dim3((W16_TOT + 255) / 256), dim3(256), 0, stream,
                     p1.in_w, p1.xproj_w, p1.out_w, p2.in_w, p2.xproj_w, p2.out_w, w16);
  // radix sort: 3 passes of (hist, scan, scatter)
  hipLaunchKernelGGL(k_hist, dim3(NST_), dim3(256), 0, stream,
                     hil1, hil2, kB, histg, 0, 1);
  hipLaunchKernelGGL(k_scanoff, dim3(8), dim3(256), 0, stream, histg, offg);
  hipLaunchKernelGGL(k_scatter, dim3(NST_), dim3(256), 0, stream,
                     hil1, hil2, kB, iB, offg, kB, iB, o_all, 0, 1, 0);
  hipLaunchKernelGGL(k_hist, dim3(NST_), dim3(256), 0, stream,
                     hil1, hil2, kB, histg, 10, 0);
  hipLaunchKernelGGL(k_scanoff, dim3(8), dim3(256), 0, stream, histg, offg);
  hipLaunchKernelGGL(k_scatter, dim3(NST_), dim3(256), 0, stream,
                     hil1, hil2, kB, iB, offg, kA, iA, o_all, 10, 0, 0);
  hipLaunchKernelGGL(k_hist, dim3(NST_), dim3(256), 0, stream,
                     hil1, hil2, kA, histg, 20, 0);
  hipLaunchKernelGGL(k_scanoff, dim3(8), dim3(256), 0, stream, histg, offg);
  hipLaunchKernelGGL(k_scatter, dim3(NST_), dim3(256), 0, stream,
                     hil1, hil2, kA, iA, offg, kB, iB, o_all, 20, 0, 1);

  hipLaunchKernelGGL(k_phaseA, dim3(NTILES_), dim3(256), 0, stream,
                     feats1, feats2, pos1, pos2, pe_w, pe_b, p1, p2, o_all, w16,
                     xc, vzb, dbl);
  hipLaunchKernelGGL(k_scan1, dim3(NCHUNKS_), dim3(256), 0, stream,
                     p1, p2, xc, dbl, hloc, sdt);
  hipLaunchKernelGGL(k_scan2, dim3(128), dim3(256), 0, stream,
                     p1, p2, hloc, sdt, hin);
  hipLaunchKernelGGL(k_scan3, dim3(NCHUNKS_), dim3(256), 0, stream,
                     p1, p2, xc, dbl, hin, vzb);
  hipLaunchKernelGGL(k_final, dim3(NTILES_), dim3(256), 0, stream,
                     vzb, o_all, w16, norm_g, norm_b, normb_g, normb_b,
                     (float*)d_out);
}